// Round 2
// baseline (464.102 us; speedup 1.0000x reference)
//
#include <hip/hip_runtime.h>
#include <hip/hip_bf16.h>
#include <cstdint>
#include <cstddef>

#define BATCH 2
#define SEQ 2048
#define DMODEL 1024
#define DIN 2048
#define NH 32
#define HEADDIM 64
#define DSTATE 64
#define DCONV 4
#define CONV_DIM (DIN + 2 * DSTATE)          // 2176
#define DPROJ (2 * DIN + 2 * DSTATE + NH)    // 4256
#define MLP_INNER 4096
#define TOKENS (BATCH * SEQ)                 // 4096
#define EPS 1e-5f
#define Q 64
#define NCHUNK (SEQ / Q)                     // 32
#define NCH (BATCH * NCHUNK * NH)            // 2048 chunk-heads
#define LSTR 72                               // 144B rows (16B-aligned)
#define NPAD_IN 4352                          // DPROJ padded to 17*256

typedef __attribute__((ext_vector_type(8))) short short8;
typedef __attribute__((ext_vector_type(8))) __bf16 bf16x8;
typedef __attribute__((ext_vector_type(4))) float f32x4;

__device__ inline short f2bf(float f) {
    unsigned u = __builtin_bit_cast(unsigned, f);
    u = (u + 0x7FFFu + ((u >> 16) & 1u)) >> 16;
    return (short)u;
}
__device__ inline float bf2f(short s) {
    unsigned u = ((unsigned)(unsigned short)s) << 16;
    return __builtin_bit_cast(float, u);
}
__device__ inline float silu_f(float x) { return x / (1.f + __expf(-x)); }

__device__ inline bf16x8 ld_frag(const short* p) {
    short8 s = *(const short8*)p;
    return __builtin_bit_cast(bf16x8, s);
}

__device__ inline void glds16(const short* g, short* l) {
    __builtin_amdgcn_global_load_lds(
        (const __attribute__((address_space(1))) void*)g,
        (__attribute__((address_space(3))) void*)l, 16, 0, 0);
}

// ================= 256x256 counted-vmcnt phased GEMM (T1+T2+T3+T4+T5) ========
// BM=BN=256, BK=64, 512 thr = 8 waves (2M x 4N), per-wave C = 128x64.
// LDS 128KB: 2 buffers x {A,B} x 2 K-halves x [256 rows x 32 k] bf16.
// Staging granularity = one 16KB K-half region (2 global_load_lds per thread).
// Schedule per K-tile t (4 sub-phases), staging tile t+1 into the other buffer:
//   P0: issue A_k0(t+1); vmcnt(6)+bar; ds_read ksub0 frags; MFMA fj{0,1}
//   P1: issue B_k0(t+1); bar;                               MFMA fj{2,3}
//   P2: issue A_k1(t+1); vmcnt(6)+bar; ds_read ksub1 frags; MFMA fj{0,1}
//   P3: issue B_k1(t+1); bar;                               MFMA fj{2,3}
// vmcnt(6) = 3 half-tiles in flight; the 4 retired loads are exactly the
// K-half needed by this phase and were issued one full K-tile earlier.
// LDS chunk layout (per 16KB region, 16B chunks): chunk(r,j) at
//   (r>>3)*32 + (r&7) + 8*j   -> each of the 32 banks serves exactly 8 dwords
// for a wave64 ds_read_b128 (throughput-minimal, conflict-free). Realized by
// pre-permuting the per-lane GLOBAL source while keeping LDS dest linear (G21).
// MODE 4: bf16 C=AB ; MODE 1: bf16 C=silu(AB+bias)
template <int MODE>
__global__ __launch_bounds__(512, 2) void gemm256_kernel(
    const short* __restrict__ A, const short* __restrict__ BT,
    void* __restrict__ Cout, const float* __restrict__ bias,
    int M, int N, int K)
{
    const int tid  = threadIdx.x;
    const int wid  = tid >> 6;
    const int lane = tid & 63;
    const int lm   = lane & 15;
    const int lg   = lane >> 4;
    const int wm   = (wid >> 2) * 128;
    const int wn   = (wid & 3) * 64;

    // XCD-aware swizzle (grids here are multiples of 8 -> bijective)
    const int nb  = gridDim.x * gridDim.y;
    const int bid = blockIdx.y * gridDim.x + blockIdx.x;
    const int per = nb >> 3;
    const int nid = (bid & 7) * per + (bid >> 3);
    const int m0  = (nid / gridDim.x) * 256;
    const int n0  = (nid % gridDim.x) * 256;

    __shared__ __attribute__((aligned(16))) short Ab[2][2][256 * 32];
    __shared__ __attribute__((aligned(16))) short Bb[2][2][256 * 32];

    f32x4 acc[8][4];
#pragma unroll
    for (int i = 0; i < 8; ++i)
#pragma unroll
        for (int j = 0; j < 4; ++j) acc[i][j] = {0.f, 0.f, 0.f, 0.f};

    // stage-source permutation: this thread's chunk c = tid (and tid+512)
    //   c -> (r = (c>>5)*8 + (c&7), j = (c>>3)&3); second load is r+128, same j
    const int q   = tid & 7;
    const int jj  = (tid >> 3) & 3;
    const int win = tid >> 5;
    const int r0  = win * 8 + q;
    const short* Asrc = A  + (size_t)(m0 + r0) * K + jj * 8;
    const short* Bsrc = BT + (size_t)(n0 + r0) * K + jj * 8;
    const size_t rstep = (size_t)128 * K;
    const int dst = wid * 512;   // shorts; wave-uniform LDS base (lane*16B added by HW)

#define STAGE(src, buf) do {                  \
        glds16((src), (buf) + dst);           \
        glds16((src) + rstep, (buf) + 4096 + dst); } while (0)

    bf16x8 af[8], bfr[4];

#define READS(As, Bs) do {                                                     \
        _Pragma("unroll")                                                      \
        for (int fi = 0; fi < 8; ++fi) {                                       \
            int rr = wm + fi * 16 + lm;                                        \
            af[fi] = ld_frag((As) + ((rr >> 3) << 8) + ((rr & 7) << 3) + (lg << 6)); \
        }                                                                      \
        _Pragma("unroll")                                                      \
        for (int fj = 0; fj < 4; ++fj) {                                       \
            int rr = wn + fj * 16 + lm;                                        \
            bfr[fj] = ld_frag((Bs) + ((rr >> 3) << 8) + ((rr & 7) << 3) + (lg << 6)); \
        }                                                                      \
    } while (0)

#define MFMAP(FJA) do {                                                        \
        __builtin_amdgcn_s_setprio(1);                                         \
        _Pragma("unroll")                                                      \
        for (int fi = 0; fi < 8; ++fi) {                                       \
            acc[fi][FJA]     = __builtin_amdgcn_mfma_f32_16x16x32_bf16(af[fi], bfr[FJA],     acc[fi][FJA],     0, 0, 0); \
            acc[fi][FJA + 1] = __builtin_amdgcn_mfma_f32_16x16x32_bf16(af[fi], bfr[FJA + 1], acc[fi][FJA + 1], 0, 0, 0); \
        }                                                                      \
        __builtin_amdgcn_s_setprio(0); } while (0)

    const int NT = K >> 6;

    // prologue: all 4 regions of tile 0 (issue order A0,B0,A1,B1 = 8 loads)
    STAGE(Asrc,      &Ab[0][0][0]);
    STAGE(Bsrc,      &Bb[0][0][0]);
    STAGE(Asrc + 32, &Ab[0][1][0]);
    STAGE(Bsrc + 32, &Bb[0][1][0]);

    for (int t = 0; t < NT - 1; ++t) {
        const int bi = t & 1, bn = bi ^ 1;
        const int kn = (t + 1) << 6;
        // ---- P0 ----
        STAGE(Asrc + kn, &Ab[bn][0][0]);
        asm volatile("s_waitcnt vmcnt(6)\n\ts_barrier" ::: "memory");
        READS(&Ab[bi][0][0], &Bb[bi][0][0]);
        MFMAP(0);
        // ---- P1 ----
        STAGE(Bsrc + kn, &Bb[bn][0][0]);
        asm volatile("s_barrier" ::: "memory");
        MFMAP(2);
        // ---- P2 ----
        STAGE(Asrc + kn + 32, &Ab[bn][1][0]);
        asm volatile("s_waitcnt vmcnt(6)\n\ts_barrier" ::: "memory");
        READS(&Ab[bi][1][0], &Bb[bi][1][0]);
        MFMAP(0);
        // ---- P3 ----
        STAGE(Bsrc + kn + 32, &Bb[bn][1][0]);
        asm volatile("s_barrier" ::: "memory");
        MFMAP(2);
    }
    // last tile: no prefetch; drain progressively (4 -> 0)
    {
        const int bi = (NT - 1) & 1;
        asm volatile("s_waitcnt vmcnt(4)\n\ts_barrier" ::: "memory");
        READS(&Ab[bi][0][0], &Bb[bi][0][0]);
        MFMAP(0);
        asm volatile("s_barrier" ::: "memory");
        MFMAP(2);
        asm volatile("s_waitcnt vmcnt(0)\n\ts_barrier" ::: "memory");
        READS(&Ab[bi][1][0], &Bb[bi][1][0]);
        MFMAP(0);
        asm volatile("s_barrier" ::: "memory");
        MFMAP(2);
    }
#undef STAGE
#undef READS
#undef MFMAP

#pragma unroll
    for (int fj = 0; fj < 4; ++fj) {
        int col = n0 + wn + fj * 16 + lm;
        if (col < N) {
            float bv = (MODE == 1) ? bias[col] : 0.f;
#pragma unroll
            for (int fi = 0; fi < 8; ++fi) {
#pragma unroll
                for (int r = 0; r < 4; ++r) {
                    int row = m0 + wm + fi * 16 + lg * 4 + r;
                    float v = acc[fi][fj][r];
                    if (MODE == 1) v = silu_f(v + bv);
                    ((short*)Cout)[(size_t)row * N + col] = f2bf(v);
                }
            }
        }
    }
}

// ---------------- bf16 GEMM: m97 staging + dbuf + XCD swizzle (N=1024 GEMMs) ----
// MODE 0: f32 C=AB; 1: bf16 C=silu(AB+bias); 2: f32 C=AB+bias+res; 3: f32 C=AB+res;
// MODE 4: bf16 C=AB.  KT=32 kernels run 4 blocks/CU; KT=64 (64KB LDS) capped at 2.
template <int MODE, int KT>
__global__ __launch_bounds__(256, (KT == 32) ? 4 : 2) void gemm_bf16_kernel(
    const short* __restrict__ A, const short* __restrict__ BT,
    void* __restrict__ Cout, const float* __restrict__ bias,
    const float* __restrict__ res, int M, int N, int K)
{
    const int tid  = threadIdx.x;
    const int wid  = tid >> 6;
    const int lane = tid & 63;
    const int lm   = lane & 15;
    const int lg   = lane >> 4;

    const int nb  = gridDim.x * gridDim.y;
    const int bid = blockIdx.y * gridDim.x + blockIdx.x;
    const int per = nb >> 3;
    const int nid = (bid & 7) * per + (bid >> 3);
    const int m0  = (nid / gridDim.x) * 128;
    const int n0  = (nid % gridDim.x) * 128;

    __shared__ __attribute__((aligned(16))) short Al0[128 * KT];
    __shared__ __attribute__((aligned(16))) short Al1[128 * KT];
    __shared__ __attribute__((aligned(16))) short Bl0[128 * KT];
    __shared__ __attribute__((aligned(16))) short Bl1[128 * KT];

    f32x4 acc[4][4];
#pragma unroll
    for (int i = 0; i < 4; ++i)
#pragma unroll
        for (int j = 0; j < 4; ++j) acc[i][j] = {0.f, 0.f, 0.f, 0.f};

    const int wm = (wid >> 1) * 64;
    const int wn = (wid & 1) * 64;

    constexpr int lpr = KT / 8;      // 16B blocks per row
    constexpr int rpi = 64 / lpr;    // rows per glds16 instr
    constexpr int nin = 32 / rpi;    // glds16 instrs per matrix per wave
    const int srow = lane / lpr;
    const int scb  = (lane % lpr) ^ (srow & (lpr - 1));   // swizzled source block
    const int scol = scb * 8;
    const short* Ag = A  + (size_t)(m0 + wid * 32 + srow) * K + scol;
    const short* Bg = BT + (size_t)(n0 + wid * 32 + srow) * K + scol;
    const int woff = wid * 32 * KT;

    const int niter = K / KT;
    {
#pragma unroll
        for (int j = 0; j < nin; ++j) {
            glds16(Ag + (size_t)j * rpi * K, Al0 + woff + j * 512);
            glds16(Bg + (size_t)j * rpi * K, Bl0 + woff + j * 512);
        }
    }

    for (int i = 0; i < niter; ++i) {
        __syncthreads();
        const short* Ac = (i & 1) ? Al1 : Al0;
        const short* Bc = (i & 1) ? Bl1 : Bl0;
        if (i + 1 < niter) {
            int kt = (i + 1) * KT;
            short* al = ((i & 1) ? Al0 : Al1) + woff;
            short* bl = ((i & 1) ? Bl0 : Bl1) + woff;
#pragma unroll
            for (int j = 0; j < nin; ++j) {
                glds16(Ag + kt + (size_t)j * rpi * K, al + j * 512);
                glds16(Bg + kt + (size_t)j * rpi * K, bl + j * 512);
            }
        }

#pragma unroll
        for (int sub = 0; sub < KT / 32; ++sub) {
            const int cb = sub * 4 + lg;
            bf16x8 af[4], bf[4];
#pragma unroll
            for (int ii = 0; ii < 4; ++ii) {
                int ar = wm + ii * 16 + lm;
                af[ii] = ld_frag(&Ac[ar * KT + ((cb ^ (ar & (lpr - 1))) * 8)]);
            }
#pragma unroll
            for (int j = 0; j < 4; ++j) {
                int br = wn + j * 16 + lm;
                bf[j] = ld_frag(&Bc[br * KT + ((cb ^ (br & (lpr - 1))) * 8)]);
            }
#pragma unroll
            for (int ii = 0; ii < 4; ++ii)
#pragma unroll
                for (int j = 0; j < 4; ++j)
                    acc[ii][j] = __builtin_amdgcn_mfma_f32_16x16x32_bf16(af[ii], bf[j], acc[ii][j], 0, 0, 0);
        }
    }

#pragma unroll
    for (int i = 0; i < 4; ++i) {
#pragma unroll
        for (int j = 0; j < 4; ++j) {
            int col = n0 + wn + j * 16 + lm;
            if (col >= N) continue;
            float bv = (MODE == 1 || MODE == 2) ? bias[col] : 0.f;
#pragma unroll
            for (int r = 0; r < 4; ++r) {
                int row = m0 + wm + i * 16 + lg * 4 + r;
                float v = acc[i][j][r];
                if (MODE == 1) {
                    ((short*)Cout)[(size_t)row * N + col] = f2bf(silu_f(v + bv));
                } else if (MODE == 4) {
                    ((short*)Cout)[(size_t)row * N + col] = f2bf(v);
                } else {
                    if (MODE == 2) v = v + bv + res[(size_t)row * N + col];
                    if (MODE == 3) v = v + res[(size_t)row * N + col];
                    ((float*)Cout)[(size_t)row * N + col] = v;
                }
            }
        }
    }
}

// ---------------- f32 -> bf16 convert ----------------
__global__ __launch_bounds__(256) void cvt_kernel(
    const float* __restrict__ src, short* __restrict__ dst, int n4)
{
    int i = (blockIdx.x * 256 + threadIdx.x);
    if (i >= n4) return;
    f32x4 v = *(const f32x4*)(src + (size_t)i * 4);
    short4 o;
    o.x = f2bf(v.x); o.y = f2bf(v.y); o.z = f2bf(v.z); o.w = f2bf(v.w);
    *(short4*)(dst + (size_t)i * 4) = o;
}

// ---------------- W [K][N] f32 -> WT [Npad][K] bf16 ----------------
__global__ __launch_bounds__(256) void transpose_kernel(
    const float* __restrict__ src, short* __restrict__ dst, int K, int N)
{
    __shared__ float t[32][33];
    int bx = blockIdx.x, by = blockIdx.y;
    int col = threadIdx.x & 31, row8 = threadIdx.x >> 5;
    int gn = bx * 32 + col;
#pragma unroll
    for (int r = 0; r < 4; ++r) {
        int gk = by * 32 + row8 + r * 8;
        t[row8 + r * 8][col] = (gn < N) ? src[(size_t)gk * N + gn] : 0.f;
    }
    __syncthreads();
#pragma unroll
    for (int r = 0; r < 4; ++r) {
        int n = bx * 32 + row8 + r * 8;
        dst[(size_t)n * K + by * 32 + col] = f2bf(t[col][row8 + r * 8]);
    }
}

// ---------------- depthwise causal conv (k=4) + bias + silu, bf16 in/out ----
#define CTOK 8
__global__ __launch_bounds__(256) void conv_kernel(
    const short* __restrict__ zx, const float* __restrict__ cw,
    const float* __restrict__ cb, short* __restrict__ xBCc)
{
    int c4 = blockIdx.y * 256 + threadIdx.x;
    if (c4 >= CONV_DIM / 4) return;
    int c  = c4 * 4;
    int m0 = blockIdx.x * CTOK;
    int l0 = m0 & (SEQ - 1);

    const short* base = zx + (size_t)m0 * DPROJ + DIN + c;
    f32x4 win[CTOK + 3];
#pragma unroll
    for (int j = 0; j < CTOK + 3; ++j) {
        int off = j - 3;
        if (l0 + off >= 0) {
            short4 sv = *(const short4*)(base + (ptrdiff_t)off * DPROJ);
            win[j] = {bf2f(sv.x), bf2f(sv.y), bf2f(sv.z), bf2f(sv.w)};
        } else {
            win[j] = {0.f, 0.f, 0.f, 0.f};
        }
    }
    f32x4 w0 = *(const f32x4*)(cw + (c + 0) * DCONV);
    f32x4 w1 = *(const f32x4*)(cw + (c + 1) * DCONV);
    f32x4 w2 = *(const f32x4*)(cw + (c + 2) * DCONV);
    f32x4 w3 = *(const f32x4*)(cw + (c + 3) * DCONV);
    f32x4 bb = *(const f32x4*)(cb + c);

    short* outp = xBCc + (size_t)m0 * CONV_DIM + c;
#pragma unroll
    for (int t = 0; t < CTOK; ++t) {
        f32x4 a = {bb.x, bb.y, bb.z, bb.w};
#pragma unroll
        for (int j = 0; j < DCONV; ++j) {
            f32x4 v = win[t + j];
            a.x += v.x * w0[j];
            a.y += v.y * w1[j];
            a.z += v.z * w2[j];
            a.w += v.w * w3[j];
        }
        short4 o;
        o.x = f2bf(silu_f(a.x)); o.y = f2bf(silu_f(a.y));
        o.z = f2bf(silu_f(a.z)); o.w = f2bf(silu_f(a.w));
        *(short4*)(outp + (size_t)t * CONV_DIM) = o;
    }
}

// ---------------- dt = softplus(dt_raw + bias); ldA = A * dt ----------------
__global__ __launch_bounds__(256) void dt_kernel(
    const short* __restrict__ zx, const float* __restrict__ dt_bias,
    const float* __restrict__ A_log, float* __restrict__ dtb, float* __restrict__ ldab)
{
    int idx = blockIdx.x * 256 + threadIdx.x;
    if (idx >= TOKENS * NH) return;
    int hh = idx & (NH - 1);
    int m  = idx >> 5;
    float v  = bf2f(zx[(size_t)m * DPROJ + DIN + CONV_DIM + hh]) + dt_bias[hh];
    float dt = (v > 20.f) ? v : log1pf(__expf(v));
    dtb[idx]  = dt;
    ldab[idx] = -__expf(A_log[hh]) * dt;
}

// ---------------- P1: intra-chunk SSD (bf16 xBCc) ----------------
__global__ __launch_bounds__(256) void chunk_kernel(
    const short* __restrict__ xBCc, const float* __restrict__ dtb,
    const float* __restrict__ ldab, float* __restrict__ ybuf,
    float* __restrict__ Sbuf, float* __restrict__ cumdecay)
{
    int bid = blockIdx.x;
    int h = bid & 31, c = (bid >> 5) & 31, b = bid >> 10;
    int m0 = b * SEQ + c * Q;
    int tid = threadIdx.x;
    int wid = tid >> 6, lane = tid & 63, lm = lane & 15, lg = lane >> 4;

    __shared__ __attribute__((aligned(16))) short Cc[64 * LSTR];
    __shared__ __attribute__((aligned(16))) short Bb[64 * LSTR];
    __shared__ __attribute__((aligned(16))) short BwT[64 * LSTR];
    __shared__ __attribute__((aligned(16))) short Xt[64 * LSTR];
    __shared__ __attribute__((aligned(16))) short Mm[64 * LSTR];
    __shared__ float Lc[64], dtv[64];

    if (tid < 64) {
        int s = tid;
        size_t ix = (size_t)(m0 + s) * NH + h;
        float ld = ldab[ix];
        float dt = dtb[ix];
        float v = ld;
#pragma unroll
        for (int off = 1; off < 64; off <<= 1) {
            float o = __shfl_up(v, off);
            if (s >= off) v += o;
        }
        Lc[s] = v;
        dtv[s] = dt;
        cumdecay[(size_t)bid * 64 + s] = __expf(v);
    }
    {
        int row = tid >> 2, c0 = (tid & 3) * 16;
        const short* pB = xBCc + (size_t)(m0 + row) * CONV_DIM + DIN;
#pragma unroll
        for (int u = 0; u < 2; ++u) {
            short8 vb = *(const short8*)(pB + c0 + 8 * u);
            short8 vc = *(const short8*)(pB + DSTATE + c0 + 8 * u);
            *(short8*)&Bb[row * LSTR + c0 + 8 * u] = vb;
            *(short8*)&Cc[row * LSTR + c0 + 8 * u] = vc;
        }
    }
    __syncthreads();
    {
        int s = tid >> 2, c0 = (tid & 3) * 16;
        float w = dtv[s];
        float w2 = __expf(Lc[63] - Lc[s]);
        const short* pX = xBCc + (size_t)(m0 + s) * CONV_DIM + h * HEADDIM;
#pragma unroll
        for (int u = 0; u < 4; ++u) {
            short4 v = *(const short4*)(pX + c0 + 4 * u);
            Xt[(c0 + 4 * u + 0) * LSTR + s] = f2bf(bf2f(v.x) * w);
            Xt[(c0 + 4 * u + 1) * LSTR + s] = f2bf(bf2f(v.y) * w);
            Xt[(c0 + 4 * u + 2) * LSTR + s] = f2bf(bf2f(v.z) * w);
            Xt[(c0 + 4 * u + 3) * LSTR + s] = f2bf(bf2f(v.w) * w);
            short4 sb = *(short4*)&Bb[s * LSTR + c0 + 4 * u];
            BwT[(c0 + 4 * u + 0) * LSTR + s] = f2bf(bf2f(sb.x) * w2);
            BwT[(c0 + 4 * u + 1) * LSTR + s] = f2bf(bf2f(sb.y) * w2);
            BwT[(c0 + 4 * u + 2) * LSTR + s] = f2bf(bf2f(sb.z) * w2);
            BwT[(c0 + 4 * u + 3) * LSTR + s] = f2bf(bf2f(sb.w) * w2);
        }
    }
    __syncthreads();

    {
        bf16x8 af[2];
#pragma unroll
        for (int kk = 0; kk < 2; ++kk)
            af[kk] = ld_frag(&Cc[(wid * 16 + lm) * LSTR + kk * 32 + lg * 8]);
#pragma unroll
        for (int j = 0; j < 4; ++j) {
            f32x4 acc = {0.f, 0.f, 0.f, 0.f};
#pragma unroll
            for (int kk = 0; kk < 2; ++kk) {
                bf16x8 bf = ld_frag(&Bb[(j * 16 + lm) * LSTR + kk * 32 + lg * 8]);
                acc = __builtin_amdgcn_mfma_f32_16x16x32_bf16(af[kk], bf, acc, 0, 0, 0);
            }
            int s = j * 16 + lm;
            float Ls = Lc[s];
#pragma unroll
            for (int r = 0; r < 4; ++r) {
                int t = wid * 16 + lg * 4 + r;
                float val = (s <= t) ? acc[r] * __expf(Lc[t] - Ls) : 0.f;
                Mm[t * LSTR + s] = f2bf(val);
            }
        }
    }
    __syncthreads();

    {
        bf16x8 am[2], aw[2];
#pragma unroll
        for (int kk = 0; kk < 2; ++kk) {
            am[kk] = ld_frag(&Mm[(wid * 16 + lm) * LSTR + kk * 32 + lg * 8]);
            aw[kk] = ld_frag(&BwT[(wid * 16 + lm) * LSTR + kk * 32 + lg * 8]);
        }
#pragma unroll
        for (int j = 0; j < 4; ++j) {
            f32x4 a1 = {0.f, 0.f, 0.f, 0.f};
            f32x4 a2 = {0.f, 0.f, 0.f, 0.f};
#pragma unroll
            for (int kk = 0; kk < 2; ++kk) {
                bf16x8 bx = ld_frag(&Xt[(j * 16 + lm) * LSTR + kk * 32 + lg * 8]);
                a1 = __builtin_amdgcn_mfma_f32_16x16x32_bf16(am[kk], bx, a1, 0, 0, 0);
                a2 = __builtin_amdgcn_mfma_f32_16x16x32_bf16(aw[kk], bx, a2, 0, 0, 0);
            }
            int p = j * 16 + lm;
#pragma unroll
            for (int r = 0; r < 4; ++r) {
                int t = wid * 16 + lg * 4 + r;
                ybuf[(size_t)(m0 + t) * DIN + h * HEADDIM + p] = a1[r];
                Sbuf[(size_t)bid * 4096 + t * 64 + p] = a2[r];
            }
        }
    }
}

// ---------------- P2: inter-chunk state recurrence ----------------
__global__ __launch_bounds__(256) void state_kernel(
    float* __restrict__ SH, const float* __restrict__ cumdecay)
{
    int bh = blockIdx.x;
    int b = bh >> 5, h = bh & 31;
    int tid = threadIdx.x;
    f32x4 H[4];
#pragma unroll
    for (int u = 0; u < 4; ++u) H[u] = {0.f, 0.f, 0.f, 0.f};
    for (int c = 0; c < NCHUNK; ++c) {
        int cid = (b * NCHUNK + c) * NH + h;
        size_t base = (size_t)cid * 4096 + (size_t)tid * 16;
        float cd = cumdecay[(size_t)cid * 64 + 63];
        f32x4 s[4];
#pragma unroll
        for (int u = 0; u < 4; ++u) s[u] = *(const f32x4*)(SH + base + u * 4);
#pragma unroll
        for (int u = 0; u < 4; ++u) *(f32x4*)(SH + base + u * 4) = H[u];
#pragma unroll
        for (int u = 0; u < 4; ++u) {
            H[u].x = cd * H[u].x + s[u].x;
            H[u].y = cd * H[u].y + s[u].y;
            H[u].z = cd * H[u].z + s[u].z;
            H[u].w = cd * H[u].w + s[u].w;
        }
    }
}

// ---------------- P3: y += exp(Lc_t) * C_t @ H_in ----------------
__global__ __launch_bounds__(256) void inter_kernel(
    const short* __restrict__ xBCc, const float* __restrict__ Hin,
    const float* __restrict__ cumdecay, float* __restrict__ ybuf)
{
    int bid = blockIdx.x;
    int h = bid & 31, c = (bid >> 5) & 31, b = bid >> 10;
    int m0 = b * SEQ + c * Q;
    int tid = threadIdx.x;
    int wid = tid >> 6, lane = tid & 63, lm = lane & 15, lg = lane >> 4;

    __shared__ __attribute__((aligned(16))) short Cc[64 * LSTR];
    __shared__ __attribute__((aligned(16))) short HT[64 * LSTR];
    __shared__ float eLc[64];

    if (tid < 64) eLc[tid] = cumdecay[(size_t)bid * 64 + tid];
    {
        int row = tid >> 2, c0 = (tid & 3) * 16;
        const short* pC = xBCc + (size_t)(m0 + row) * CONV_DIM + DIN + DSTATE;
#pragma unroll
        for (int u = 0; u < 2; ++u) {
            short8 vc = *(const short8*)(pC + c0 + 8 * u);
            *(short8*)&Cc[row * LSTR + c0 + 8 * u] = vc;
        }
        const float* pH = Hin + (size_t)bid * 4096 + row * 64;
#pragma unroll
        for (int u = 0; u < 4; ++u) {
            f32x4 vh = *(const f32x4*)(pH + c0 + 4 * u);
            HT[(c0 + 4 * u + 0) * LSTR + row] = f2bf(vh.x);
            HT[(c0 + 4 * u + 1) * LSTR + row] = f2bf(vh.y);
            HT[(c0 + 4 * u + 2) * LSTR + row] = f2bf(vh.z);
            HT[(c0 + 4 * u + 3) * LSTR + row] = f2bf(vh.w);
        }
    }
    __syncthreads();

    bf16x8 af[2];
#pragma unroll
    for (int kk = 0; kk < 2; ++kk)
        af[kk] = ld_frag(&Cc[(wid * 16 + lm) * LSTR + kk * 32 + lg * 8]);
#pragma unroll
    for (int j = 0; j < 4; ++j) {
        f32x4 acc = {0.f, 0.f, 0.f, 0.f};
#pragma unroll
        for (int kk = 0; kk < 2; ++kk) {
            bf16x8 bh_ = ld_frag(&HT[(j * 16 + lm) * LSTR + kk * 32 + lg * 8]);
            acc = __builtin_amdgcn_mfma_f32_16x16x32_bf16(af[kk], bh_, acc, 0, 0, 0);
        }
        int p = j * 16 + lm;
#pragma unroll
        for (int r = 0; r < 4; ++r) {
            int t = wid * 16 + lg * 4 + r;
            size_t ya = (size_t)(m0 + t) * DIN + h * HEADDIM + p;
            ybuf[ya] += eLc[t] * acc[r];
        }
    }
}

// ---------------- ybf = bf16(rmsnorm((y + D*x) * silu(z), norm_w)) ----------------
__global__ __launch_bounds__(256) void norm1_kernel(
    const short* __restrict__ zx, const short* __restrict__ xBCc,
    const float* __restrict__ Dp, const float* __restrict__ y,
    short* __restrict__ ybf, const float* __restrict__ w)
{
    int m = blockIdx.x;
    int t = threadIdx.x;
    const short* zr = zx + (size_t)m * DPROJ;
    const short* xr = xBCc + (size_t)m * CONV_DIM;
    const float* yr = y + (size_t)m * DIN;
    float vals[8];
    float ss = 0.f;
#pragma unroll
    for (int j = 0; j < 8; ++j) {
        int i = j * 256 + t;
        float v = (yr[i] + Dp[i >> 6] * bf2f(xr[i])) * silu_f(bf2f(zr[i]));
        vals[j] = v;
        ss += v * v;
    }
#pragma unroll
    for (int o = 32; o >= 1; o >>= 1) ss += __shfl_xor(ss, o);
    __shared__ float wsum[4];
    if ((t & 63) == 0) wsum[t >> 6] = ss;
    __syncthreads();
    float tot = wsum[0] + wsum[1] + wsum[2] + wsum[3];
    float scale = rsqrtf(tot / (float)DIN + EPS);
#pragma unroll
    for (int j = 0; j < 8; ++j) {
        int i = j * 256 + t;
        ybf[(size_t)m * DIN + i] = f2bf(vals[j] * scale * w[i]);
    }
}

// ---------------- hnbf = bf16(rmsnorm(h, rms_w)) ----------------
__global__ __launch_bounds__(256) void norm2_kernel(
    const float* __restrict__ hb, short* __restrict__ hnbf, const float* __restrict__ w)
{
    int m = blockIdx.x;
    int t = threadIdx.x;
    const float* hr = hb + (size_t)m * DMODEL;
    float vals[4];
    float ss = 0.f;
#pragma unroll
    for (int j = 0; j < 4; ++j) {
        int i = j * 256 + t;
        float v = hr[i];
        vals[j] = v;
        ss += v * v;
    }
#pragma unroll
    for (int o = 32; o >= 1; o >>= 1) ss += __shfl_xor(ss, o);
    __shared__ float wsum[4];
    if ((t & 63) == 0) wsum[t >> 6] = ss;
    __syncthreads();
    float tot = wsum[0] + wsum[1] + wsum[2] + wsum[3];
    float scale = rsqrtf(tot / (float)DMODEL + EPS);
#pragma unroll
    for (int j = 0; j < 4; ++j) {
        int i = j * 256 + t;
        hnbf[(size_t)m * DMODEL + i] = f2bf(vals[j] * scale * w[i]);
    }
}

extern "C" void kernel_launch(void* const* d_in, const int* in_sizes, int n_in,
                              void* d_out, int out_size, void* d_ws, size_t ws_size,
                              hipStream_t stream) {
    const float* x       = (const float*)d_in[0];
    const float* W_in    = (const float*)d_in[1];
    const float* conv_w  = (const float*)d_in[2];
    const float* conv_b  = (const float*)d_in[3];
    const float* dt_bias = (const float*)d_in[4];
    const float* A_log   = (const float*)d_in[5];
    const float* D_param = (const float*)d_in[6];
    const float* norm_w  = (const float*)d_in[7];
    const float* W_out   = (const float*)d_in[8];
    const float* rms_w   = (const float*)d_in[9];
    const float* mlp_w1  = (const float*)d_in[10];
    const float* mlp_b1  = (const float*)d_in[11];
    const float* mlp_w2  = (const float*)d_in[12];
    const float* mlp_b2  = (const float*)d_in[13];
    float* out = (float*)d_out;

    // Workspace layout (region sizes kept from R8; zx/xBCc now bf16 within
    // their old f32-sized slots — wasteful but safe).
    float* ws       = (float*)d_ws;
    float* zxf      = ws;                                  // holds bf16 zx
    float* xBCf     = zxf + (size_t)TOKENS * DPROJ;        // holds bf16 xBCc
    float* dtb      = xBCf + (size_t)TOKENS * CONV_DIM;
    float* ldab     = dtb + (size_t)TOKENS * NH;
    float* cumdecay = ldab + (size_t)TOKENS * NH;
    float* ybuf     = cumdecay + (size_t)TOKENS * NH;
    float* SH       = ybuf + (size_t)TOKENS * DIN;
    float* bfarea   = SH + (size_t)NCH * 4096;

    short* zxb   = (short*)zxf;
    short* xBCb  = (short*)xBCf;
    short* xbf   = (short*)ybuf;
    short* midbf = (short*)ybuf;
    float* hbuf  = SH;
    short* hnbf  = (short*)(SH + (size_t)TOKENS * DMODEL);

    short* ybf   = (short*)bfarea;
    short* WinT  = ybf + (size_t)TOKENS * DIN;
    short* WoutT = WinT + (size_t)NPAD_IN * DMODEL;
    short* w1T   = WoutT + (size_t)DMODEL * DIN;
    short* w2T   = w1T + (size_t)MLP_INNER * DMODEL;

    dim3 blk(256);
    dim3 blk2(512);

    // 0. conversions / weight transposes
    cvt_kernel<<<dim3(TOKENS * DMODEL / 4 / 256), blk, 0, stream>>>(x, xbf, TOKENS * DMODEL / 4);
    transpose_kernel<<<dim3(NPAD_IN / 32, DMODEL / 32), blk, 0, stream>>>(W_in, WinT, DMODEL, DPROJ);
    transpose_kernel<<<dim3(DMODEL / 32, DIN / 32), blk, 0, stream>>>(W_out, WoutT, DIN, DMODEL);
    transpose_kernel<<<dim3(MLP_INNER / 32, DMODEL / 32), blk, 0, stream>>>(mlp_w1, w1T, DMODEL, MLP_INNER);
    transpose_kernel<<<dim3(DMODEL / 32, MLP_INNER / 32), blk, 0, stream>>>(mlp_w2, w2T, MLP_INNER, DMODEL);

    // 1. zx = bf16(x @ W_in)  (256^2 phased kernel: 17x16 = 272 blocks)
    gemm256_kernel<4><<<dim3(NPAD_IN / 256, TOKENS / 256), blk2, 0, stream>>>(
        xbf, WinT, zxb, nullptr, TOKENS, DPROJ, DMODEL);
    // 2. conv + bias + silu (bf16 in/out, token-blocked)
    conv_kernel<<<dim3(TOKENS / CTOK, (CONV_DIM / 4 + 255) / 256), blk, 0, stream>>>(
        zxb, conv_w, conv_b, xBCb);
    // 3. dt / ldA
    dt_kernel<<<dim3(TOKENS * NH / 256), blk, 0, stream>>>(zxb, dt_bias, A_log, dtb, ldab);
    // 4. SSD
    chunk_kernel<<<dim3(NCH), blk, 0, stream>>>(xBCb, dtb, ldab, ybuf, SH, cumdecay);
    state_kernel<<<dim3(BATCH * NH), blk, 0, stream>>>(SH, cumdecay);
    inter_kernel<<<dim3(NCH), blk, 0, stream>>>(xBCb, SH, cumdecay, ybuf);
    // 5. ybf = bf16(rmsnorm((y + D*x) * silu(z)))
    norm1_kernel<<<dim3(TOKENS), blk, 0, stream>>>(zxb, xBCb, D_param, ybuf, ybf, norm_w);
    // 6. h = x + ybf @ W_out  (N=1024 -> 128^2 path, 256 blocks, KT=64)
    gemm_bf16_kernel<3, 64><<<dim3(DMODEL / 128, TOKENS / 128), blk, 0, stream>>>(
        ybf, WoutT, hbuf, nullptr, x, TOKENS, DMODEL, DIN);
    // 7. hnbf = bf16(rmsnorm(h))
    norm2_kernel<<<dim3(TOKENS), blk, 0, stream>>>(hbuf, hnbf, rms_w);
    // 8. midbf = bf16(silu(hnbf @ mlp_w1 + b1))  (256^2 phased kernel: 16x16 = 256 blocks)
    gemm256_kernel<1><<<dim3(MLP_INNER / 256, TOKENS / 256), blk2, 0, stream>>>(
        hnbf, w1T, midbf, mlp_b1, TOKENS, MLP_INNER, DMODEL);
    // 9. out = h + midbf @ mlp_w2 + b2  (N=1024 -> 128^2 path, 256 blocks, KT=64)
    gemm_bf16_kernel<2, 64><<<dim3(DMODEL / 128, TOKENS / 128), blk, 0, stream>>>(
        midbf, w2T, out, mlp_b2, hbuf, TOKENS, DMODEL, MLP_INNER);
}

// Round 3
// 421.685 us; speedup vs baseline: 1.1006x; 1.1006x over previous
//
#include <hip/hip_runtime.h>
#include <hip/hip_bf16.h>
#include <cstdint>
#include <cstddef>

#define BATCH 2
#define SEQ 2048
#define DMODEL 1024
#define DIN 2048
#define NH 32
#define HEADDIM 64
#define DSTATE 64
#define DCONV 4
#define CONV_DIM (DIN + 2 * DSTATE)          // 2176
#define DPROJ (2 * DIN + 2 * DSTATE + NH)    // 4256
#define MLP_INNER 4096
#define TOKENS (BATCH * SEQ)                 // 4096
#define EPS 1e-5f
#define Q 64
#define NCHUNK (SEQ / Q)                     // 32
#define NCH (BATCH * NCHUNK * NH)            // 2048 chunk-heads
#define LSTR 72                               // 144B rows (16B-aligned)
#define NPAD_IN 4352                          // DPROJ padded to 34*128

typedef __attribute__((ext_vector_type(8))) short short8;
typedef __attribute__((ext_vector_type(8))) __bf16 bf16x8;
typedef __attribute__((ext_vector_type(4))) float f32x4;

__device__ inline short f2bf(float f) {
    unsigned u = __builtin_bit_cast(unsigned, f);
    u = (u + 0x7FFFu + ((u >> 16) & 1u)) >> 16;
    return (short)u;
}
__device__ inline float bf2f(short s) {
    unsigned u = ((unsigned)(unsigned short)s) << 16;
    return __builtin_bit_cast(float, u);
}
__device__ inline float silu_f(float x) { return x / (1.f + __expf(-x)); }

__device__ inline bf16x8 ld_frag(const short* p) {
    short8 s = *(const short8*)p;
    return __builtin_bit_cast(bf16x8, s);
}

__device__ inline void glds16(const short* g, short* l) {
    __builtin_amdgcn_global_load_lds(
        (const __attribute__((address_space(1))) void*)g,
        (__attribute__((address_space(3))) void*)l, 16, 0, 0);
}

// ================= 256x256 counted-vmcnt phased GEMM (m201-style) ==========
// BM=BN=256, BK=64, 512 thr = 8 waves (2M x 4N), per-wave C = 128x64.
// LDS 128KB: 2 buffers x {A,B} x 2 K-halves x [256 rows x 32 k] bf16.
// ONLY used for grids that are exactly <= 256 blocks (1 round at 1 blk/CU).
//
// Phase structure per K-tile t (regions A0,B0,A1,B1 staged for t+1):
//   P0: rd af_k0[4..7]+bfr_k0[0,1]; stage A0; bar; lgkm0; MFMA k0 fj01
//   P1: rd bfr_k0[2,3];            stage B0; vmcnt(4)+bar; lgkm0; MFMA k0 fj23;
//       tail-rd af_k1[0..3]   (A1(t),B1(t) retired by this vmcnt)
//   P2: rd af_k1[4..7]+bfr_k1[0,1]; stage A1; bar; lgkm0; MFMA k1 fj01
//   P3: rd bfr_k1[2,3];            stage B1; vmcnt(4)+bar; lgkm0; MFMA k1 fj23;
//       tail-rd af_k0(t+1)[0..3] (A0(t+1),B0(t+1) retired by this vmcnt)
// => 6 ds_read_b128/phase (even LDS load), 16 MFMA/phase, every region is
// consumed >=1 phase after the vmcnt+barrier that retires its loads.
// Ledger (per-wave outstanding vm-ops): P0 stage -> 6; P1 stage -> 8,
// vmcnt(4) retires A1(t)+B1(t); P2 -> 6; P3 -> 8, vmcnt(4) retires
// A0(t+1)+B0(t+1). Write-after-read windows all >=2 barriers.
// LDS chunk layout per 16KB region: chunk(r,j) at (r>>3)*32 + (r&7) + 8*j
// -> conflict-free ds_read_b128; realized via pre-permuted global source (G21).
// MODE 4: bf16 C=AB ; MODE 1: bf16 C=silu(AB+bias)
template <int MODE>
__global__ __launch_bounds__(512, 2) void gemm256_kernel(
    const short* __restrict__ A, const short* __restrict__ BT,
    void* __restrict__ Cout, const float* __restrict__ bias,
    int M, int N, int K)
{
    const int tid  = threadIdx.x;
    const int wid  = tid >> 6;
    const int lane = tid & 63;
    const int lm   = lane & 15;
    const int lg   = lane >> 4;
    const int wm   = (wid >> 2) * 128;
    const int wn   = (wid & 3) * 64;

    // XCD-aware swizzle (grids here are multiples of 8 -> bijective)
    const int nb  = gridDim.x * gridDim.y;
    const int bid = blockIdx.y * gridDim.x + blockIdx.x;
    const int per = nb >> 3;
    const int nid = (bid & 7) * per + (bid >> 3);
    const int m0  = (nid / gridDim.x) * 256;
    const int n0  = (nid % gridDim.x) * 256;

    __shared__ __attribute__((aligned(16))) short Ab[2][2][256 * 32];
    __shared__ __attribute__((aligned(16))) short Bb[2][2][256 * 32];

    f32x4 acc[8][4];
#pragma unroll
    for (int i = 0; i < 8; ++i)
#pragma unroll
        for (int j = 0; j < 4; ++j) acc[i][j] = {0.f, 0.f, 0.f, 0.f};

    // stage-source permutation: this thread's chunk c = tid (and tid+512)
    //   c -> (r = (c>>5)*8 + (c&7), j = (c>>3)&3); second load is r+128, same j
    const int q   = tid & 7;
    const int jj  = (tid >> 3) & 3;
    const int win = tid >> 5;
    const int r0  = win * 8 + q;
    const short* Asrc = A  + (size_t)(m0 + r0) * K + jj * 8;
    const short* Bsrc = BT + (size_t)(n0 + r0) * K + jj * 8;
    const size_t rstep = (size_t)128 * K;
    const int dst = wid * 512;   // shorts; wave-uniform LDS base (lane*16B added by HW)

#define STAGE(src, buf) do {                  \
        glds16((src), (buf) + dst);           \
        glds16((src) + rstep, (buf) + 4096 + dst); } while (0)

    bf16x8 af[8], bfr[4];

#define READ_A(As, i0, i1) do {                                                \
        _Pragma("unroll")                                                      \
        for (int fi = (i0); fi < (i1); ++fi) {                                 \
            int rr = wm + fi * 16 + lm;                                        \
            af[fi] = ld_frag((As) + ((rr >> 3) << 8) + ((rr & 7) << 3) + (lg << 6)); \
        }                                                                      \
    } while (0)

#define READ_B(Bs, j0, j1) do {                                                \
        _Pragma("unroll")                                                      \
        for (int fj = (j0); fj < (j1); ++fj) {                                 \
            int rr = wn + fj * 16 + lm;                                        \
            bfr[fj] = ld_frag((Bs) + ((rr >> 3) << 8) + ((rr & 7) << 3) + (lg << 6)); \
        }                                                                      \
    } while (0)

#define MFMAP(FJA) do {                                                        \
        __builtin_amdgcn_s_setprio(1);                                         \
        _Pragma("unroll")                                                      \
        for (int fi = 0; fi < 8; ++fi) {                                       \
            acc[fi][FJA]     = __builtin_amdgcn_mfma_f32_16x16x32_bf16(af[fi], bfr[FJA],     acc[fi][FJA],     0, 0, 0); \
            acc[fi][FJA + 1] = __builtin_amdgcn_mfma_f32_16x16x32_bf16(af[fi], bfr[FJA + 1], acc[fi][FJA + 1], 0, 0, 0); \
        }                                                                      \
        __builtin_amdgcn_s_setprio(0); } while (0)

#define BAR()      asm volatile("s_barrier" ::: "memory")
#define VM4_BAR()  asm volatile("s_waitcnt vmcnt(4)\n\ts_barrier" ::: "memory")
#define VM0_BAR()  asm volatile("s_waitcnt vmcnt(0)\n\ts_barrier" ::: "memory")
#define LGKM0()    asm volatile("s_waitcnt lgkmcnt(0)" ::: "memory")

    const int NT = K >> 6;

    // prologue: stage all 4 regions of tile 0, retire A0,B0, pre-read af_k0[0..3]
    STAGE(Asrc,      &Ab[0][0][0]);
    STAGE(Bsrc,      &Bb[0][0][0]);
    STAGE(Asrc + 32, &Ab[0][1][0]);
    STAGE(Bsrc + 32, &Bb[0][1][0]);
    VM4_BAR();
    READ_A(&Ab[0][0][0], 0, 4);

    for (int t = 0; t < NT - 1; ++t) {
        const int bi = t & 1, bn = bi ^ 1;
        const int kn = (t + 1) << 6;
        const short* A0c = &Ab[bi][0][0];
        const short* B0c = &Bb[bi][0][0];
        const short* A1c = &Ab[bi][1][0];
        const short* B1c = &Bb[bi][1][0];
        // ---- P0 ----
        READ_A(A0c, 4, 8); READ_B(B0c, 0, 2);
        STAGE(Asrc + kn, &Ab[bn][0][0]);
        BAR(); LGKM0();
        MFMAP(0);
        // ---- P1 ----
        READ_B(B0c, 2, 4);
        STAGE(Bsrc + kn, &Bb[bn][0][0]);
        VM4_BAR(); LGKM0();
        MFMAP(2);
        READ_A(A1c, 0, 4);              // tail: af_k1[0..3] (A1(t) just retired)
        // ---- P2 ----
        READ_A(A1c, 4, 8); READ_B(B1c, 0, 2);
        STAGE(Asrc + kn + 32, &Ab[bn][1][0]);
        BAR(); LGKM0();
        MFMAP(0);
        // ---- P3 ----
        READ_B(B1c, 2, 4);
        STAGE(Bsrc + kn + 32, &Bb[bn][1][0]);
        VM4_BAR(); LGKM0();
        MFMAP(2);
        READ_A(&Ab[bn][0][0], 0, 4);    // tail: af_k0(t+1)[0..3] (A0(t+1) retired)
    }
    // peeled last tile: no stages; drain 4 -> 0
    {
        const int bi = (NT - 1) & 1;
        const short* A0c = &Ab[bi][0][0];
        const short* B0c = &Bb[bi][0][0];
        const short* A1c = &Ab[bi][1][0];
        const short* B1c = &Bb[bi][1][0];
        // P0
        READ_A(A0c, 4, 8); READ_B(B0c, 0, 2);
        BAR(); LGKM0();
        MFMAP(0);
        // P1
        READ_B(B0c, 2, 4);
        VM0_BAR(); LGKM0();
        MFMAP(2);
        READ_A(A1c, 0, 4);
        // P2
        READ_A(A1c, 4, 8); READ_B(B1c, 0, 2);
        BAR(); LGKM0();
        MFMAP(0);
        // P3
        READ_B(B1c, 2, 4);
        BAR(); LGKM0();
        MFMAP(2);
    }
#undef STAGE
#undef READ_A
#undef READ_B
#undef MFMAP
#undef BAR
#undef VM4_BAR
#undef VM0_BAR
#undef LGKM0

#pragma unroll
    for (int fj = 0; fj < 4; ++fj) {
        int col = n0 + wn + fj * 16 + lm;
        if (col < N) {
            float bv = (MODE == 1) ? bias[col] : 0.f;
#pragma unroll
            for (int fi = 0; fi < 8; ++fi) {
#pragma unroll
                for (int r = 0; r < 4; ++r) {
                    int row = m0 + wm + fi * 16 + lg * 4 + r;
                    float v = acc[fi][fj][r];
                    if (MODE == 1) v = silu_f(v + bv);
                    ((short*)Cout)[(size_t)row * N + col] = f2bf(v);
                }
            }
        }
    }
}

// ---------------- bf16 GEMM: m97 staging + dbuf + XCD swizzle + XOR-swizzled LDS ----
// MODE 0: f32 C=AB; 1: bf16 C=silu(AB+bias); 2: f32 C=AB+bias+res; 3: f32 C=AB+res;
// MODE 4: bf16 C=AB.  KT=32 kernels run 4 blocks/CU; KT=64 (64KB LDS) capped at 2.
template <int MODE, int KT>
__global__ __launch_bounds__(256, (KT == 32) ? 4 : 2) void gemm_bf16_kernel(
    const short* __restrict__ A, const short* __restrict__ BT,
    void* __restrict__ Cout, const float* __restrict__ bias,
    const float* __restrict__ res, int M, int N, int K)
{
    const int tid  = threadIdx.x;
    const int wid  = tid >> 6;
    const int lane = tid & 63;
    const int lm   = lane & 15;
    const int lg   = lane >> 4;

    const int nb  = gridDim.x * gridDim.y;
    const int bid = blockIdx.y * gridDim.x + blockIdx.x;
    const int per = nb >> 3;
    const int nid = (bid & 7) * per + (bid >> 3);
    const int m0  = (nid / gridDim.x) * 128;
    const int n0  = (nid % gridDim.x) * 128;

    __shared__ __attribute__((aligned(16))) short Al0[128 * KT];
    __shared__ __attribute__((aligned(16))) short Al1[128 * KT];
    __shared__ __attribute__((aligned(16))) short Bl0[128 * KT];
    __shared__ __attribute__((aligned(16))) short Bl1[128 * KT];

    f32x4 acc[4][4];
#pragma unroll
    for (int i = 0; i < 4; ++i)
#pragma unroll
        for (int j = 0; j < 4; ++j) acc[i][j] = {0.f, 0.f, 0.f, 0.f};

    const int wm = (wid >> 1) * 64;
    const int wn = (wid & 1) * 64;

    constexpr int lpr = KT / 8;      // 16B blocks per row
    constexpr int rpi = 64 / lpr;    // rows per glds16 instr
    constexpr int nin = 32 / rpi;    // glds16 instrs per matrix per wave
    const int srow = lane / lpr;
    const int scb  = (lane % lpr) ^ (srow & (lpr - 1));   // swizzled source block
    const int scol = scb * 8;
    const short* Ag = A  + (size_t)(m0 + wid * 32 + srow) * K + scol;
    const short* Bg = BT + (size_t)(n0 + wid * 32 + srow) * K + scol;
    const int woff = wid * 32 * KT;

    const int niter = K / KT;
    {
#pragma unroll
        for (int j = 0; j < nin; ++j) {
            glds16(Ag + (size_t)j * rpi * K, Al0 + woff + j * 512);
            glds16(Bg + (size_t)j * rpi * K, Bl0 + woff + j * 512);
        }
    }

    for (int i = 0; i < niter; ++i) {
        __syncthreads();
        const short* Ac = (i & 1) ? Al1 : Al0;
        const short* Bc = (i & 1) ? Bl1 : Bl0;
        if (i + 1 < niter) {
            int kt = (i + 1) * KT;
            short* al = ((i & 1) ? Al0 : Al1) + woff;
            short* bl = ((i & 1) ? Bl0 : Bl1) + woff;
#pragma unroll
            for (int j = 0; j < nin; ++j) {
                glds16(Ag + kt + (size_t)j * rpi * K, al + j * 512);
                glds16(Bg + kt + (size_t)j * rpi * K, bl + j * 512);
            }
        }

#pragma unroll
        for (int sub = 0; sub < KT / 32; ++sub) {
            const int cb = sub * 4 + lg;
            bf16x8 af[4], bf[4];
#pragma unroll
            for (int ii = 0; ii < 4; ++ii) {
                int ar = wm + ii * 16 + lm;
                af[ii] = ld_frag(&Ac[ar * KT + ((cb ^ (ar & (lpr - 1))) * 8)]);
            }
#pragma unroll
            for (int j = 0; j < 4; ++j) {
                int br = wn + j * 16 + lm;
                bf[j] = ld_frag(&Bc[br * KT + ((cb ^ (br & (lpr - 1))) * 8)]);
            }
#pragma unroll
            for (int ii = 0; ii < 4; ++ii)
#pragma unroll
                for (int j = 0; j < 4; ++j)
                    acc[ii][j] = __builtin_amdgcn_mfma_f32_16x16x32_bf16(af[ii], bf[j], acc[ii][j], 0, 0, 0);
        }
    }

#pragma unroll
    for (int i = 0; i < 4; ++i) {
#pragma unroll
        for (int j = 0; j < 4; ++j) {
            int col = n0 + wn + j * 16 + lm;
            if (col >= N) continue;
            float bv = (MODE == 1 || MODE == 2) ? bias[col] : 0.f;
#pragma unroll
            for (int r = 0; r < 4; ++r) {
                int row = m0 + wm + i * 16 + lg * 4 + r;
                float v = acc[i][j][r];
                if (MODE == 1) {
                    ((short*)Cout)[(size_t)row * N + col] = f2bf(silu_f(v + bv));
                } else if (MODE == 4) {
                    ((short*)Cout)[(size_t)row * N + col] = f2bf(v);
                } else {
                    if (MODE == 2) v = v + bv + res[(size_t)row * N + col];
                    if (MODE == 3) v = v + res[(size_t)row * N + col];
                    ((float*)Cout)[(size_t)row * N + col] = v;
                }
            }
        }
    }
}

// ---------------- f32 -> bf16 convert ----------------
__global__ __launch_bounds__(256) void cvt_kernel(
    const float* __restrict__ src, short* __restrict__ dst, int n4)
{
    int i = (blockIdx.x * 256 + threadIdx.x);
    if (i >= n4) return;
    f32x4 v = *(const f32x4*)(src + (size_t)i * 4);
    short4 o;
    o.x = f2bf(v.x); o.y = f2bf(v.y); o.z = f2bf(v.z); o.w = f2bf(v.w);
    *(short4*)(dst + (size_t)i * 4) = o;
}

// ---------------- W [K][N] f32 -> WT [Npad][K] bf16 ----------------
__global__ __launch_bounds__(256) void transpose_kernel(
    const float* __restrict__ src, short* __restrict__ dst, int K, int N)
{
    __shared__ float t[32][33];
    int bx = blockIdx.x, by = blockIdx.y;
    int col = threadIdx.x & 31, row8 = threadIdx.x >> 5;
    int gn = bx * 32 + col;
#pragma unroll
    for (int r = 0; r < 4; ++r) {
        int gk = by * 32 + row8 + r * 8;
        t[row8 + r * 8][col] = (gn < N) ? src[(size_t)gk * N + gn] : 0.f;
    }
    __syncthreads();
#pragma unroll
    for (int r = 0; r < 4; ++r) {
        int n = bx * 32 + row8 + r * 8;
        dst[(size_t)n * K + by * 32 + col] = f2bf(t[col][row8 + r * 8]);
    }
}

// ---------------- depthwise causal conv (k=4) + bias + silu, bf16 in/out ----
#define CTOK 8
__global__ __launch_bounds__(256) void conv_kernel(
    const short* __restrict__ zx, const float* __restrict__ cw,
    const float* __restrict__ cb, short* __restrict__ xBCc)
{
    int c4 = blockIdx.y * 256 + threadIdx.x;
    if (c4 >= CONV_DIM / 4) return;
    int c  = c4 * 4;
    int m0 = blockIdx.x * CTOK;
    int l0 = m0 & (SEQ - 1);

    const short* base = zx + (size_t)m0 * DPROJ + DIN + c;
    f32x4 win[CTOK + 3];
#pragma unroll
    for (int j = 0; j < CTOK + 3; ++j) {
        int off = j - 3;
        if (l0 + off >= 0) {
            short4 sv = *(const short4*)(base + (ptrdiff_t)off * DPROJ);
            win[j] = {bf2f(sv.x), bf2f(sv.y), bf2f(sv.z), bf2f(sv.w)};
        } else {
            win[j] = {0.f, 0.f, 0.f, 0.f};
        }
    }
    f32x4 w0 = *(const f32x4*)(cw + (c + 0) * DCONV);
    f32x4 w1 = *(const f32x4*)(cw + (c + 1) * DCONV);
    f32x4 w2 = *(const f32x4*)(cw + (c + 2) * DCONV);
    f32x4 w3 = *(const f32x4*)(cw + (c + 3) * DCONV);
    f32x4 bb = *(const f32x4*)(cb + c);

    short* outp = xBCc + (size_t)m0 * CONV_DIM + c;
#pragma unroll
    for (int t = 0; t < CTOK; ++t) {
        f32x4 a = {bb.x, bb.y, bb.z, bb.w};
#pragma unroll
        for (int j = 0; j < DCONV; ++j) {
            f32x4 v = win[t + j];
            a.x += v.x * w0[j];
            a.y += v.y * w1[j];
            a.z += v.z * w2[j];
            a.w += v.w * w3[j];
        }
        short4 o;
        o.x = f2bf(silu_f(a.x)); o.y = f2bf(silu_f(a.y));
        o.z = f2bf(silu_f(a.z)); o.w = f2bf(silu_f(a.w));
        *(short4*)(outp + (size_t)t * CONV_DIM) = o;
    }
}

// ---------------- dt = softplus(dt_raw + bias); ldA = A * dt ----------------
__global__ __launch_bounds__(256) void dt_kernel(
    const short* __restrict__ zx, const float* __restrict__ dt_bias,
    const float* __restrict__ A_log, float* __restrict__ dtb, float* __restrict__ ldab)
{
    int idx = blockIdx.x * 256 + threadIdx.x;
    if (idx >= TOKENS * NH) return;
    int hh = idx & (NH - 1);
    int m  = idx >> 5;
    float v  = bf2f(zx[(size_t)m * DPROJ + DIN + CONV_DIM + hh]) + dt_bias[hh];
    float dt = (v > 20.f) ? v : log1pf(__expf(v));
    dtb[idx]  = dt;
    ldab[idx] = -__expf(A_log[hh]) * dt;
}

// ---------------- P1: intra-chunk SSD (bf16 xBCc) ----------------
__global__ __launch_bounds__(256) void chunk_kernel(
    const short* __restrict__ xBCc, const float* __restrict__ dtb,
    const float* __restrict__ ldab, float* __restrict__ ybuf,
    float* __restrict__ Sbuf, float* __restrict__ cumdecay)
{
    int bid = blockIdx.x;
    int h = bid & 31, c = (bid >> 5) & 31, b = bid >> 10;
    int m0 = b * SEQ + c * Q;
    int tid = threadIdx.x;
    int wid = tid >> 6, lane = tid & 63, lm = lane & 15, lg = lane >> 4;

    __shared__ __attribute__((aligned(16))) short Cc[64 * LSTR];
    __shared__ __attribute__((aligned(16))) short Bb[64 * LSTR];
    __shared__ __attribute__((aligned(16))) short BwT[64 * LSTR];
    __shared__ __attribute__((aligned(16))) short Xt[64 * LSTR];
    __shared__ __attribute__((aligned(16))) short Mm[64 * LSTR];
    __shared__ float Lc[64], dtv[64];

    if (tid < 64) {
        int s = tid;
        size_t ix = (size_t)(m0 + s) * NH + h;
        float ld = ldab[ix];
        float dt = dtb[ix];
        float v = ld;
#pragma unroll
        for (int off = 1; off < 64; off <<= 1) {
            float o = __shfl_up(v, off);
            if (s >= off) v += o;
        }
        Lc[s] = v;
        dtv[s] = dt;
        cumdecay[(size_t)bid * 64 + s] = __expf(v);
    }
    {
        int row = tid >> 2, c0 = (tid & 3) * 16;
        const short* pB = xBCc + (size_t)(m0 + row) * CONV_DIM + DIN;
#pragma unroll
        for (int u = 0; u < 2; ++u) {
            short8 vb = *(const short8*)(pB + c0 + 8 * u);
            short8 vc = *(const short8*)(pB + DSTATE + c0 + 8 * u);
            *(short8*)&Bb[row * LSTR + c0 + 8 * u] = vb;
            *(short8*)&Cc[row * LSTR + c0 + 8 * u] = vc;
        }
    }
    __syncthreads();
    {
        int s = tid >> 2, c0 = (tid & 3) * 16;
        float w = dtv[s];
        float w2 = __expf(Lc[63] - Lc[s]);
        const short* pX = xBCc + (size_t)(m0 + s) * CONV_DIM + h * HEADDIM;
#pragma unroll
        for (int u = 0; u < 4; ++u) {
            short4 v = *(const short4*)(pX + c0 + 4 * u);
            Xt[(c0 + 4 * u + 0) * LSTR + s] = f2bf(bf2f(v.x) * w);
            Xt[(c0 + 4 * u + 1) * LSTR + s] = f2bf(bf2f(v.y) * w);
            Xt[(c0 + 4 * u + 2) * LSTR + s] = f2bf(bf2f(v.z) * w);
            Xt[(c0 + 4 * u + 3) * LSTR + s] = f2bf(bf2f(v.w) * w);
            short4 sb = *(short4*)&Bb[s * LSTR + c0 + 4 * u];
            BwT[(c0 + 4 * u + 0) * LSTR + s] = f2bf(bf2f(sb.x) * w2);
            BwT[(c0 + 4 * u + 1) * LSTR + s] = f2bf(bf2f(sb.y) * w2);
            BwT[(c0 + 4 * u + 2) * LSTR + s] = f2bf(bf2f(sb.z) * w2);
            BwT[(c0 + 4 * u + 3) * LSTR + s] = f2bf(bf2f(sb.w) * w2);
        }
    }
    __syncthreads();

    {
        bf16x8 af[2];
#pragma unroll
        for (int kk = 0; kk < 2; ++kk)
            af[kk] = ld_frag(&Cc[(wid * 16 + lm) * LSTR + kk * 32 + lg * 8]);
#pragma unroll
        for (int j = 0; j < 4; ++j) {
            f32x4 acc = {0.f, 0.f, 0.f, 0.f};
#pragma unroll
            for (int kk = 0; kk < 2; ++kk) {
                bf16x8 bf = ld_frag(&Bb[(j * 16 + lm) * LSTR + kk * 32 + lg * 8]);
                acc = __builtin_amdgcn_mfma_f32_16x16x32_bf16(af[kk], bf, acc, 0, 0, 0);
            }
            int s = j * 16 + lm;
            float Ls = Lc[s];
#pragma unroll
            for (int r = 0; r < 4; ++r) {
                int t = wid * 16 + lg * 4 + r;
                float val = (s <= t) ? acc[r] * __expf(Lc[t] - Ls) : 0.f;
                Mm[t * LSTR + s] = f2bf(val);
            }
        }
    }
    __syncthreads();

    {
        bf16x8 am[2], aw[2];
#pragma unroll
        for (int kk = 0; kk < 2; ++kk) {
            am[kk] = ld_frag(&Mm[(wid * 16 + lm) * LSTR + kk * 32 + lg * 8]);
            aw[kk] = ld_frag(&BwT[(wid * 16 + lm) * LSTR + kk * 32 + lg * 8]);
        }
#pragma unroll
        for (int j = 0; j < 4; ++j) {
            f32x4 a1 = {0.f, 0.f, 0.f, 0.f};
            f32x4 a2 = {0.f, 0.f, 0.f, 0.f};
#pragma unroll
            for (int kk = 0; kk < 2; ++kk) {
                bf16x8 bx = ld_frag(&Xt[(j * 16 + lm) * LSTR + kk * 32 + lg * 8]);
                a1 = __builtin_amdgcn_mfma_f32_16x16x32_bf16(am[kk], bx, a1, 0, 0, 0);
                a2 = __builtin_amdgcn_mfma_f32_16x16x32_bf16(aw[kk], bx, a2, 0, 0, 0);
            }
            int p = j * 16 + lm;
#pragma unroll
            for (int r = 0; r < 4; ++r) {
                int t = wid * 16 + lg * 4 + r;
                ybuf[(size_t)(m0 + t) * DIN + h * HEADDIM + p] = a1[r];
                Sbuf[(size_t)bid * 4096 + t * 64 + p] = a2[r];
            }
        }
    }
}

// ---------------- P2: inter-chunk state recurrence ----------------
__global__ __launch_bounds__(256) void state_kernel(
    float* __restrict__ SH, const float* __restrict__ cumdecay)
{
    int bh = blockIdx.x;
    int b = bh >> 5, h = bh & 31;
    int tid = threadIdx.x;
    f32x4 H[4];
#pragma unroll
    for (int u = 0; u < 4; ++u) H[u] = {0.f, 0.f, 0.f, 0.f};
    for (int c = 0; c < NCHUNK; ++c) {
        int cid = (b * NCHUNK + c) * NH + h;
        size_t base = (size_t)cid * 4096 + (size_t)tid * 16;
        float cd = cumdecay[(size_t)cid * 64 + 63];
        f32x4 s[4];
#pragma unroll
        for (int u = 0; u < 4; ++u) s[u] = *(const f32x4*)(SH + base + u * 4);
#pragma unroll
        for (int u = 0; u < 4; ++u) *(f32x4*)(SH + base + u * 4) = H[u];
#pragma unroll
        for (int u = 0; u < 4; ++u) {
            H[u].x = cd * H[u].x + s[u].x;
            H[u].y = cd * H[u].y + s[u].y;
            H[u].z = cd * H[u].z + s[u].z;
            H[u].w = cd * H[u].w + s[u].w;
        }
    }
}

// ---------------- P3: y += exp(Lc_t) * C_t @ H_in ----------------
__global__ __launch_bounds__(256) void inter_kernel(
    const short* __restrict__ xBCc, const float* __restrict__ Hin,
    const float* __restrict__ cumdecay, float* __restrict__ ybuf)
{
    int bid = blockIdx.x;
    int h = bid & 31, c = (bid >> 5) & 31, b = bid >> 10;
    int m0 = b * SEQ + c * Q;
    int tid = threadIdx.x;
    int wid = tid >> 6, lane = tid & 63, lm = lane & 15, lg = lane >> 4;

    __shared__ __attribute__((aligned(16))) short Cc[64 * LSTR];
    __shared__ __attribute__((aligned(16))) short HT[64 * LSTR];
    __shared__ float eLc[64];

    if (tid < 64) eLc[tid] = cumdecay[(size_t)bid * 64 + tid];
    {
        int row = tid >> 2, c0 = (tid & 3) * 16;
        const short* pC = xBCc + (size_t)(m0 + row) * CONV_DIM + DIN + DSTATE;
#pragma unroll
        for (int u = 0; u < 2; ++u) {
            short8 vc = *(const short8*)(pC + c0 + 8 * u);
            *(short8*)&Cc[row * LSTR + c0 + 8 * u] = vc;
        }
        const float* pH = Hin + (size_t)bid * 4096 + row * 64;
#pragma unroll
        for (int u = 0; u < 4; ++u) {
            f32x4 vh = *(const f32x4*)(pH + c0 + 4 * u);
            HT[(c0 + 4 * u + 0) * LSTR + row] = f2bf(vh.x);
            HT[(c0 + 4 * u + 1) * LSTR + row] = f2bf(vh.y);
            HT[(c0 + 4 * u + 2) * LSTR + row] = f2bf(vh.z);
            HT[(c0 + 4 * u + 3) * LSTR + row] = f2bf(vh.w);
        }
    }
    __syncthreads();

    bf16x8 af[2];
#pragma unroll
    for (int kk = 0; kk < 2; ++kk)
        af[kk] = ld_frag(&Cc[(wid * 16 + lm) * LSTR + kk * 32 + lg * 8]);
#pragma unroll
    for (int j = 0; j < 4; ++j) {
        f32x4 acc = {0.f, 0.f, 0.f, 0.f};
#pragma unroll
        for (int kk = 0; kk < 2; ++kk) {
            bf16x8 bh_ = ld_frag(&HT[(j * 16 + lm) * LSTR + kk * 32 + lg * 8]);
            acc = __builtin_amdgcn_mfma_f32_16x16x32_bf16(af[kk], bh_, acc, 0, 0, 0);
        }
        int p = j * 16 + lm;
#pragma unroll
        for (int r = 0; r < 4; ++r) {
            int t = wid * 16 + lg * 4 + r;
            size_t ya = (size_t)(m0 + t) * DIN + h * HEADDIM + p;
            ybuf[ya] += eLc[t] * acc[r];
        }
    }
}

// ---------------- ybf = bf16(rmsnorm((y + D*x) * silu(z), norm_w)) ----------------
__global__ __launch_bounds__(256) void norm1_kernel(
    const short* __restrict__ zx, const short* __restrict__ xBCc,
    const float* __restrict__ Dp, const float* __restrict__ y,
    short* __restrict__ ybf, const float* __restrict__ w)
{
    int m = blockIdx.x;
    int t = threadIdx.x;
    const short* zr = zx + (size_t)m * DPROJ;
    const short* xr = xBCc + (size_t)m * CONV_DIM;
    const float* yr = y + (size_t)m * DIN;
    float vals[8];
    float ss = 0.f;
#pragma unroll
    for (int j = 0; j < 8; ++j) {
        int i = j * 256 + t;
        float v = (yr[i] + Dp[i >> 6] * bf2f(xr[i])) * silu_f(bf2f(zr[i]));
        vals[j] = v;
        ss += v * v;
    }
#pragma unroll
    for (int o = 32; o >= 1; o >>= 1) ss += __shfl_xor(ss, o);
    __shared__ float wsum[4];
    if ((t & 63) == 0) wsum[t >> 6] = ss;
    __syncthreads();
    float tot = wsum[0] + wsum[1] + wsum[2] + wsum[3];
    float scale = rsqrtf(tot / (float)DIN + EPS);
#pragma unroll
    for (int j = 0; j < 8; ++j) {
        int i = j * 256 + t;
        ybf[(size_t)m * DIN + i] = f2bf(vals[j] * scale * w[i]);
    }
}

// ---------------- hnbf = bf16(rmsnorm(h, rms_w)) ----------------
__global__ __launch_bounds__(256) void norm2_kernel(
    const float* __restrict__ hb, short* __restrict__ hnbf, const float* __restrict__ w)
{
    int m = blockIdx.x;
    int t = threadIdx.x;
    const float* hr = hb + (size_t)m * DMODEL;
    float vals[4];
    float ss = 0.f;
#pragma unroll
    for (int j = 0; j < 4; ++j) {
        int i = j * 256 + t;
        float v = hr[i];
        vals[j] = v;
        ss += v * v;
    }
#pragma unroll
    for (int o = 32; o >= 1; o >>= 1) ss += __shfl_xor(ss, o);
    __shared__ float wsum[4];
    if ((t & 63) == 0) wsum[t >> 6] = ss;
    __syncthreads();
    float tot = wsum[0] + wsum[1] + wsum[2] + wsum[3];
    float scale = rsqrtf(tot / (float)DMODEL + EPS);
#pragma unroll
    for (int j = 0; j < 4; ++j) {
        int i = j * 256 + t;
        hnbf[(size_t)m * DMODEL + i] = f2bf(vals[j] * scale * w[i]);
    }
}

extern "C" void kernel_launch(void* const* d_in, const int* in_sizes, int n_in,
                              void* d_out, int out_size, void* d_ws, size_t ws_size,
                              hipStream_t stream) {
    const float* x       = (const float*)d_in[0];
    const float* W_in    = (const float*)d_in[1];
    const float* conv_w  = (const float*)d_in[2];
    const float* conv_b  = (const float*)d_in[3];
    const float* dt_bias = (const float*)d_in[4];
    const float* A_log   = (const float*)d_in[5];
    const float* D_param = (const float*)d_in[6];
    const float* norm_w  = (const float*)d_in[7];
    const float* W_out   = (const float*)d_in[8];
    const float* rms_w   = (const float*)d_in[9];
    const float* mlp_w1  = (const float*)d_in[10];
    const float* mlp_b1  = (const float*)d_in[11];
    const float* mlp_w2  = (const float*)d_in[12];
    const float* mlp_b2  = (const float*)d_in[13];
    float* out = (float*)d_out;

    // Workspace layout (region sizes kept from R8; zx/xBCc now bf16 within
    // their old f32-sized slots — wasteful but safe).
    float* ws       = (float*)d_ws;
    float* zxf      = ws;                                  // holds bf16 zx
    float* xBCf     = zxf + (size_t)TOKENS * DPROJ;        // holds bf16 xBCc
    float* dtb      = xBCf + (size_t)TOKENS * CONV_DIM;
    float* ldab     = dtb + (size_t)TOKENS * NH;
    float* cumdecay = ldab + (size_t)TOKENS * NH;
    float* ybuf     = cumdecay + (size_t)TOKENS * NH;
    float* SH       = ybuf + (size_t)TOKENS * DIN;
    float* bfarea   = SH + (size_t)NCH * 4096;

    short* zxb   = (short*)zxf;
    short* xBCb  = (short*)xBCf;
    short* xbf   = (short*)ybuf;
    short* midbf = (short*)ybuf;
    float* hbuf  = SH;
    short* hnbf  = (short*)(SH + (size_t)TOKENS * DMODEL);

    short* ybf   = (short*)bfarea;
    short* WinT  = ybf + (size_t)TOKENS * DIN;
    short* WoutT = WinT + (size_t)NPAD_IN * DMODEL;
    short* w1T   = WoutT + (size_t)DMODEL * DIN;
    short* w2T   = w1T + (size_t)MLP_INNER * DMODEL;

    dim3 blk(256);
    dim3 blk2(512);

    // 0. conversions / weight transposes
    cvt_kernel<<<dim3(TOKENS * DMODEL / 4 / 256), blk, 0, stream>>>(x, xbf, TOKENS * DMODEL / 4);
    transpose_kernel<<<dim3(NPAD_IN / 32, DMODEL / 32), blk, 0, stream>>>(W_in, WinT, DMODEL, DPROJ);
    transpose_kernel<<<dim3(DMODEL / 32, DIN / 32), blk, 0, stream>>>(W_out, WoutT, DIN, DMODEL);
    transpose_kernel<<<dim3(MLP_INNER / 32, DMODEL / 32), blk, 0, stream>>>(mlp_w1, w1T, DMODEL, MLP_INNER);
    transpose_kernel<<<dim3(DMODEL / 32, MLP_INNER / 32), blk, 0, stream>>>(mlp_w2, w2T, MLP_INNER, DMODEL);

    // 1. zx = bf16(x @ W_in)  (1088 blocks -> 128^2 KT=32 path, 4 blk/CU;
    //    272 tiles of 256^2 would run 2 rounds at 1 blk/CU -> 2x tail, R2 lesson)
    gemm_bf16_kernel<4, 32><<<dim3(NPAD_IN / 128, TOKENS / 128), blk, 0, stream>>>(
        xbf, WinT, zxb, nullptr, nullptr, TOKENS, DPROJ, DMODEL);
    // 2. conv + bias + silu (bf16 in/out, token-blocked)
    conv_kernel<<<dim3(TOKENS / CTOK, (CONV_DIM / 4 + 255) / 256), blk, 0, stream>>>(
        zxb, conv_w, conv_b, xBCb);
    // 3. dt / ldA
    dt_kernel<<<dim3(TOKENS * NH / 256), blk, 0, stream>>>(zxb, dt_bias, A_log, dtb, ldab);
    // 4. SSD
    chunk_kernel<<<dim3(NCH), blk, 0, stream>>>(xBCb, dtb, ldab, ybuf, SH, cumdecay);
    state_kernel<<<dim3(BATCH * NH), blk, 0, stream>>>(SH, cumdecay);
    inter_kernel<<<dim3(NCH), blk, 0, stream>>>(xBCb, SH, cumdecay, ybuf);
    // 5. ybf = bf16(rmsnorm((y + D*x) * silu(z)))
    norm1_kernel<<<dim3(TOKENS), blk, 0, stream>>>(zxb, xBCb, D_param, ybuf, ybf, norm_w);
    // 6. h = x + ybf @ W_out  (N=1024 -> 128^2 path, 256 blocks, KT=64)
    gemm_bf16_kernel<3, 64><<<dim3(DMODEL / 128, TOKENS / 128), blk, 0, stream>>>(
        ybf, WoutT, hbuf, nullptr, x, TOKENS, DMODEL, DIN);
    // 7. hnbf = bf16(rmsnorm(h))
    norm2_kernel<<<dim3(TOKENS), blk, 0, stream>>>(hbuf, hnbf, rms_w);
    // 8. midbf = bf16(silu(hnbf @ mlp_w1 + b1))  (256^2 phased: 16x16 = 256 blocks, 1 round)
    gemm256_kernel<1><<<dim3(MLP_INNER / 256, TOKENS / 256), blk2, 0, stream>>>(
        hnbf, w1T, midbf, mlp_b1, TOKENS, MLP_INNER, DMODEL);
    // 9. out = h + midbf @ mlp_w2 + b2  (N=1024 -> 128^2 path, 256 blocks, KT=64)
    gemm_bf16_kernel<2, 64><<<dim3(DMODEL / 128, TOKENS / 128), blk, 0, stream>>>(
        midbf, w2T, out, mlp_b2, hbuf, TOKENS, DMODEL, MLP_INNER);
}

// Round 4
// 407.607 us; speedup vs baseline: 1.1386x; 1.0345x over previous
//
#include <hip/hip_runtime.h>
#include <hip/hip_bf16.h>
#include <cstdint>
#include <cstddef>

#define BATCH 2
#define SEQ 2048
#define DMODEL 1024
#define DIN 2048
#define NH 32
#define HEADDIM 64
#define DSTATE 64
#define DCONV 4
#define CONV_DIM (DIN + 2 * DSTATE)          // 2176
#define DPROJ (2 * DIN + 2 * DSTATE + NH)    // 4256
#define MLP_INNER 4096
#define TOKENS (BATCH * SEQ)                 // 4096
#define EPS 1e-5f
#define Q 64
#define NCHUNK (SEQ / Q)                     // 32
#define NCH (BATCH * NCHUNK * NH)            // 2048 chunk-heads
#define LSTR 72                               // 144B rows (16B-aligned)
#define NPAD_IN 4352                          // DPROJ padded to 34*128

typedef __attribute__((ext_vector_type(8))) short short8;
typedef __attribute__((ext_vector_type(8))) __bf16 bf16x8;
typedef __attribute__((ext_vector_type(4))) float f32x4;

__device__ inline short f2bf(float f) {
    unsigned u = __builtin_bit_cast(unsigned, f);
    u = (u + 0x7FFFu + ((u >> 16) & 1u)) >> 16;
    return (short)u;
}
__device__ inline float bf2f(short s) {
    unsigned u = ((unsigned)(unsigned short)s) << 16;
    return __builtin_bit_cast(float, u);
}
__device__ inline float silu_f(float x) { return x / (1.f + __expf(-x)); }

__device__ inline bf16x8 ld_frag(const short* p) {
    short8 s = *(const short8*)p;
    return __builtin_bit_cast(bf16x8, s);
}

__device__ inline void glds16(const short* g, short* l) {
    __builtin_amdgcn_global_load_lds(
        (const __attribute__((address_space(1))) void*)g,
        (__attribute__((address_space(3))) void*)l, 16, 0, 0);
}

// ================= 256x256 counted-vmcnt phased GEMM (m201-style) ==========
// Used ONLY for the MLP-up GEMM (256 blocks = exactly 1 round at 1 blk/CU).
// Best measured config for that GEMM (63.4 us, R3); schedule left unchanged
// (two reconstruction attempts measured 75 -> 63 us; further schedule work
// frozen pending ability to inspect .s — see R3 post-mortem).
template <int MODE>
__global__ __launch_bounds__(512, 2) void gemm256_kernel(
    const short* __restrict__ A, const short* __restrict__ BT,
    void* __restrict__ Cout, const float* __restrict__ bias,
    int M, int N, int K)
{
    const int tid  = threadIdx.x;
    const int wid  = tid >> 6;
    const int lane = tid & 63;
    const int lm   = lane & 15;
    const int lg   = lane >> 4;
    const int wm   = (wid >> 2) * 128;
    const int wn   = (wid & 3) * 64;

    const int nb  = gridDim.x * gridDim.y;
    const int bid = blockIdx.y * gridDim.x + blockIdx.x;
    const int per = nb >> 3;
    const int nid = (bid & 7) * per + (bid >> 3);
    const int m0  = (nid / gridDim.x) * 256;
    const int n0  = (nid % gridDim.x) * 256;

    __shared__ __attribute__((aligned(16))) short Ab[2][2][256 * 32];
    __shared__ __attribute__((aligned(16))) short Bb[2][2][256 * 32];

    f32x4 acc[8][4];
#pragma unroll
    for (int i = 0; i < 8; ++i)
#pragma unroll
        for (int j = 0; j < 4; ++j) acc[i][j] = {0.f, 0.f, 0.f, 0.f};

    const int q   = tid & 7;
    const int jj  = (tid >> 3) & 3;
    const int win = tid >> 5;
    const int r0  = win * 8 + q;
    const short* Asrc = A  + (size_t)(m0 + r0) * K + jj * 8;
    const short* Bsrc = BT + (size_t)(n0 + r0) * K + jj * 8;
    const size_t rstep = (size_t)128 * K;
    const int dst = wid * 512;

#define STAGE(src, buf) do {                  \
        glds16((src), (buf) + dst);           \
        glds16((src) + rstep, (buf) + 4096 + dst); } while (0)

    bf16x8 af[8], bfr[4];

#define READ_A(As, i0, i1) do {                                                \
        _Pragma("unroll")                                                      \
        for (int fi = (i0); fi < (i1); ++fi) {                                 \
            int rr = wm + fi * 16 + lm;                                        \
            af[fi] = ld_frag((As) + ((rr >> 3) << 8) + ((rr & 7) << 3) + (lg << 6)); \
        }                                                                      \
    } while (0)

#define READ_B(Bs, j0, j1) do {                                                \
        _Pragma("unroll")                                                      \
        for (int fj = (j0); fj < (j1); ++fj) {                                 \
            int rr = wn + fj * 16 + lm;                                        \
            bfr[fj] = ld_frag((Bs) + ((rr >> 3) << 8) + ((rr & 7) << 3) + (lg << 6)); \
        }                                                                      \
    } while (0)

#define MFMAP(FJA) do {                                                        \
        __builtin_amdgcn_s_setprio(1);                                         \
        _Pragma("unroll")                                                      \
        for (int fi = 0; fi < 8; ++fi) {                                       \
            acc[fi][FJA]     = __builtin_amdgcn_mfma_f32_16x16x32_bf16(af[fi], bfr[FJA],     acc[fi][FJA],     0, 0, 0); \
            acc[fi][FJA + 1] = __builtin_amdgcn_mfma_f32_16x16x32_bf16(af[fi], bfr[FJA + 1], acc[fi][FJA + 1], 0, 0, 0); \
        }                                                                      \
        __builtin_amdgcn_s_setprio(0); } while (0)

#define BAR()      asm volatile("s_barrier" ::: "memory")
#define VM4_BAR()  asm volatile("s_waitcnt vmcnt(4)\n\ts_barrier" ::: "memory")
#define VM0_BAR()  asm volatile("s_waitcnt vmcnt(0)\n\ts_barrier" ::: "memory")
#define LGKM0()    asm volatile("s_waitcnt lgkmcnt(0)" ::: "memory")

    const int NT = K >> 6;

    STAGE(Asrc,      &Ab[0][0][0]);
    STAGE(Bsrc,      &Bb[0][0][0]);
    STAGE(Asrc + 32, &Ab[0][1][0]);
    STAGE(Bsrc + 32, &Bb[0][1][0]);
    VM4_BAR();
    READ_A(&Ab[0][0][0], 0, 4);

    for (int t = 0; t < NT - 1; ++t) {
        const int bi = t & 1, bn = bi ^ 1;
        const int kn = (t + 1) << 6;
        const short* A0c = &Ab[bi][0][0];
        const short* B0c = &Bb[bi][0][0];
        const short* A1c = &Ab[bi][1][0];
        const short* B1c = &Bb[bi][1][0];
        // ---- P0 ----
        READ_A(A0c, 4, 8); READ_B(B0c, 0, 2);
        STAGE(Asrc + kn, &Ab[bn][0][0]);
        BAR(); LGKM0();
        MFMAP(0);
        // ---- P1 ----
        READ_B(B0c, 2, 4);
        STAGE(Bsrc + kn, &Bb[bn][0][0]);
        VM4_BAR(); LGKM0();
        MFMAP(2);
        READ_A(A1c, 0, 4);
        // ---- P2 ----
        READ_A(A1c, 4, 8); READ_B(B1c, 0, 2);
        STAGE(Asrc + kn + 32, &Ab[bn][1][0]);
        BAR(); LGKM0();
        MFMAP(0);
        // ---- P3 ----
        READ_B(B1c, 2, 4);
        STAGE(Bsrc + kn + 32, &Bb[bn][1][0]);
        VM4_BAR(); LGKM0();
        MFMAP(2);
        READ_A(&Ab[bn][0][0], 0, 4);
    }
    {
        const int bi = (NT - 1) & 1;
        const short* A0c = &Ab[bi][0][0];
        const short* B0c = &Bb[bi][0][0];
        const short* A1c = &Ab[bi][1][0];
        const short* B1c = &Bb[bi][1][0];
        READ_A(A0c, 4, 8); READ_B(B0c, 0, 2);
        BAR(); LGKM0();
        MFMAP(0);
        READ_B(B0c, 2, 4);
        VM0_BAR(); LGKM0();
        MFMAP(2);
        READ_A(A1c, 0, 4);
        READ_A(A1c, 4, 8); READ_B(B1c, 0, 2);
        BAR(); LGKM0();
        MFMAP(0);
        READ_B(B1c, 2, 4);
        BAR(); LGKM0();
        MFMAP(2);
    }
#undef STAGE
#undef READ_A
#undef READ_B
#undef MFMAP
#undef BAR
#undef VM4_BAR
#undef VM0_BAR
#undef LGKM0

#pragma unroll
    for (int fj = 0; fj < 4; ++fj) {
        int col = n0 + wn + fj * 16 + lm;
        if (col < N) {
            float bv = (MODE == 1) ? bias[col] : 0.f;
#pragma unroll
            for (int fi = 0; fi < 8; ++fi) {
#pragma unroll
                for (int r = 0; r < 4; ++r) {
                    int row = m0 + wm + fi * 16 + lg * 4 + r;
                    float v = acc[fi][fj][r];
                    if (MODE == 1) v = silu_f(v + bv);
                    ((short*)Cout)[(size_t)row * N + col] = f2bf(v);
                }
            }
        }
    }
}

// ---------------- bf16 GEMM: m97 staging + dbuf + XCD swizzle (128x128) ----
// MODE 4: bf16 C=AB (GEMM1). KT=32 -> 4 blocks/CU.
template <int MODE, int KT>
__global__ __launch_bounds__(256, (KT == 32) ? 4 : 2) void gemm_bf16_kernel(
    const short* __restrict__ A, const short* __restrict__ BT,
    void* __restrict__ Cout, const float* __restrict__ bias,
    const float* __restrict__ res, int M, int N, int K)
{
    const int tid  = threadIdx.x;
    const int wid  = tid >> 6;
    const int lane = tid & 63;
    const int lm   = lane & 15;
    const int lg   = lane >> 4;

    const int nb  = gridDim.x * gridDim.y;
    const int bid = blockIdx.y * gridDim.x + blockIdx.x;
    const int per = nb >> 3;
    const int nid = (bid & 7) * per + (bid >> 3);
    const int m0  = (nid / gridDim.x) * 128;
    const int n0  = (nid % gridDim.x) * 128;

    __shared__ __attribute__((aligned(16))) short Al0[128 * KT];
    __shared__ __attribute__((aligned(16))) short Al1[128 * KT];
    __shared__ __attribute__((aligned(16))) short Bl0[128 * KT];
    __shared__ __attribute__((aligned(16))) short Bl1[128 * KT];

    f32x4 acc[4][4];
#pragma unroll
    for (int i = 0; i < 4; ++i)
#pragma unroll
        for (int j = 0; j < 4; ++j) acc[i][j] = {0.f, 0.f, 0.f, 0.f};

    const int wm = (wid >> 1) * 64;
    const int wn = (wid & 1) * 64;

    constexpr int lpr = KT / 8;      // 16B blocks per row
    constexpr int rpi = 64 / lpr;    // rows per glds16 instr
    constexpr int nin = 32 / rpi;    // glds16 instrs per matrix per wave
    const int srow = lane / lpr;
    const int scb  = (lane % lpr) ^ (srow & (lpr - 1));   // swizzled source block
    const int scol = scb * 8;
    const short* Ag = A  + (size_t)(m0 + wid * 32 + srow) * K + scol;
    const short* Bg = BT + (size_t)(n0 + wid * 32 + srow) * K + scol;
    const int woff = wid * 32 * KT;

    const int niter = K / KT;
    {
#pragma unroll
        for (int j = 0; j < nin; ++j) {
            glds16(Ag + (size_t)j * rpi * K, Al0 + woff + j * 512);
            glds16(Bg + (size_t)j * rpi * K, Bl0 + woff + j * 512);
        }
    }

    for (int i = 0; i < niter; ++i) {
        __syncthreads();
        const short* Ac = (i & 1) ? Al1 : Al0;
        const short* Bc = (i & 1) ? Bl1 : Bl0;
        if (i + 1 < niter) {
            int kt = (i + 1) * KT;
            short* al = ((i & 1) ? Al0 : Al1) + woff;
            short* bl = ((i & 1) ? Bl0 : Bl1) + woff;
#pragma unroll
            for (int j = 0; j < nin; ++j) {
                glds16(Ag + kt + (size_t)j * rpi * K, al + j * 512);
                glds16(Bg + kt + (size_t)j * rpi * K, bl + j * 512);
            }
        }

#pragma unroll
        for (int sub = 0; sub < KT / 32; ++sub) {
            const int cb = sub * 4 + lg;
            bf16x8 af[4], bf[4];
#pragma unroll
            for (int ii = 0; ii < 4; ++ii) {
                int ar = wm + ii * 16 + lm;
                af[ii] = ld_frag(&Ac[ar * KT + ((cb ^ (ar & (lpr - 1))) * 8)]);
            }
#pragma unroll
            for (int j = 0; j < 4; ++j) {
                int br = wn + j * 16 + lm;
                bf[j] = ld_frag(&Bc[br * KT + ((cb ^ (br & (lpr - 1))) * 8)]);
            }
#pragma unroll
            for (int ii = 0; ii < 4; ++ii)
#pragma unroll
                for (int j = 0; j < 4; ++j)
                    acc[ii][j] = __builtin_amdgcn_mfma_f32_16x16x32_bf16(af[ii], bf[j], acc[ii][j], 0, 0, 0);
        }
    }

#pragma unroll
    for (int i = 0; i < 4; ++i) {
#pragma unroll
        for (int j = 0; j < 4; ++j) {
            int col = n0 + wn + j * 16 + lm;
            if (col >= N) continue;
            float bv = (MODE == 1 || MODE == 2) ? bias[col] : 0.f;
#pragma unroll
            for (int r = 0; r < 4; ++r) {
                int row = m0 + wm + i * 16 + lg * 4 + r;
                float v = acc[i][j][r];
                if (MODE == 1) {
                    ((short*)Cout)[(size_t)row * N + col] = f2bf(silu_f(v + bv));
                } else if (MODE == 4) {
                    ((short*)Cout)[(size_t)row * N + col] = f2bf(v);
                } else {
                    if (MODE == 2) v = v + bv + res[(size_t)row * N + col];
                    if (MODE == 3) v = v + res[(size_t)row * N + col];
                    ((float*)Cout)[(size_t)row * N + col] = v;
                }
            }
        }
    }
}

// ---------------- 64x128-tile bf16 GEMM, KT=64 (N=1024 GEMMs) --------------
// 256 thr = 4 waves; wave w: output rows 0..63 (fi=4), cols w*32 (fj=2).
// Grid (N/128) x (M/64) = 8 x 64 = 512 blocks -> exactly 2 blk/CU (48KB LDS),
// so two blocks interleave and hide each other's barrier drains (m97 lesson:
// the 2-barrier K-step needs co-resident blocks; 256-block 128^2 grids ran
// 1 blk/CU with nothing to overlap).
// MODE 2: f32 C=AB+bias+res ; MODE 3: f32 C=AB+res.
template <int MODE>
__global__ __launch_bounds__(256, 2) void gemm64_kernel(
    const short* __restrict__ A, const short* __restrict__ BT,
    float* __restrict__ Cout, const float* __restrict__ bias,
    const float* __restrict__ res, int M, int N, int K)
{
    constexpr int KT = 64;
    const int tid  = threadIdx.x;
    const int wid  = tid >> 6;
    const int lane = tid & 63;
    const int lm   = lane & 15;
    const int lg   = lane >> 4;
    const int wn   = wid * 32;

    const int nb  = gridDim.x * gridDim.y;
    const int bid = blockIdx.y * gridDim.x + blockIdx.x;
    const int per = nb >> 3;
    const int nid = (bid & 7) * per + (bid >> 3);
    const int m0  = (nid / gridDim.x) * 64;
    const int n0  = (nid % gridDim.x) * 128;

    __shared__ __attribute__((aligned(16))) short Al0[64 * KT];
    __shared__ __attribute__((aligned(16))) short Al1[64 * KT];
    __shared__ __attribute__((aligned(16))) short Bl0[128 * KT];
    __shared__ __attribute__((aligned(16))) short Bl1[128 * KT];

    f32x4 acc[4][2];
#pragma unroll
    for (int i = 0; i < 4; ++i)
#pragma unroll
        for (int j = 0; j < 2; ++j) acc[i][j] = {0.f, 0.f, 0.f, 0.f};

    // staging: lpr=8 chunks/row, rpi=8 rows/instr, 4 instrs per 32-row slab.
    // B: all 4 waves stage rows wid*32..+31. A: waves 0,1 stage rows wid*32..+31.
    const int srow = lane >> 3;
    const int scb  = (lane & 7) ^ (srow & 7);
    const int scol = scb * 8;
    const short* Bg = BT + (size_t)(n0 + wid * 32 + srow) * K + scol;
    const short* Ag = A  + (size_t)(m0 + (wid & 1) * 32 + srow) * K + scol;
    const int woffB = wid * 32 * KT;
    const int woffA = (wid & 1) * 32 * KT;
    const bool doA = (wid < 2);

    const int niter = K / KT;
    {
#pragma unroll
        for (int j = 0; j < 4; ++j) {
            if (doA) glds16(Ag + (size_t)j * 8 * K, Al0 + woffA + j * 512);
            glds16(Bg + (size_t)j * 8 * K, Bl0 + woffB + j * 512);
        }
    }

    for (int i = 0; i < niter; ++i) {
        __syncthreads();
        const short* Ac = (i & 1) ? Al1 : Al0;
        const short* Bc = (i & 1) ? Bl1 : Bl0;
        if (i + 1 < niter) {
            int kt = (i + 1) * KT;
            short* al = ((i & 1) ? Al0 : Al1) + woffA;
            short* bl = ((i & 1) ? Bl0 : Bl1) + woffB;
#pragma unroll
            for (int j = 0; j < 4; ++j) {
                if (doA) glds16(Ag + kt + (size_t)j * 8 * K, al + j * 512);
                glds16(Bg + kt + (size_t)j * 8 * K, bl + j * 512);
            }
        }

#pragma unroll
        for (int sub = 0; sub < 2; ++sub) {
            const int cb = sub * 4 + lg;
            bf16x8 af[4], bf[2];
#pragma unroll
            for (int ii = 0; ii < 4; ++ii) {
                int ar = ii * 16 + lm;
                af[ii] = ld_frag(&Ac[ar * KT + ((cb ^ (ar & 7)) * 8)]);
            }
#pragma unroll
            for (int j = 0; j < 2; ++j) {
                int br = wn + j * 16 + lm;
                bf[j] = ld_frag(&Bc[br * KT + ((cb ^ (br & 7)) * 8)]);
            }
#pragma unroll
            for (int ii = 0; ii < 4; ++ii)
#pragma unroll
                for (int j = 0; j < 2; ++j)
                    acc[ii][j] = __builtin_amdgcn_mfma_f32_16x16x32_bf16(af[ii], bf[j], acc[ii][j], 0, 0, 0);
        }
    }

#pragma unroll
    for (int j = 0; j < 2; ++j) {
        int col = n0 + wn + j * 16 + lm;
        float bv = (MODE == 2) ? bias[col] : 0.f;
#pragma unroll
        for (int i = 0; i < 4; ++i) {
#pragma unroll
            for (int r = 0; r < 4; ++r) {
                int row = m0 + i * 16 + lg * 4 + r;
                float v = acc[i][j][r] + bv + res[(size_t)row * N + col];
                Cout[(size_t)row * N + col] = v;
            }
        }
    }
}

// ---------------- f32 -> bf16 convert ----------------
__global__ __launch_bounds__(256) void cvt_kernel(
    const float* __restrict__ src, short* __restrict__ dst, int n4)
{
    int i = (blockIdx.x * 256 + threadIdx.x);
    if (i >= n4) return;
    f32x4 v = *(const f32x4*)(src + (size_t)i * 4);
    short4 o;
    o.x = f2bf(v.x); o.y = f2bf(v.y); o.z = f2bf(v.z); o.w = f2bf(v.w);
    *(short4*)(dst + (size_t)i * 4) = o;
}

// ---------------- W [K][N] f32 -> WT [Npad][K] bf16 ----------------
__global__ __launch_bounds__(256) void transpose_kernel(
    const float* __restrict__ src, short* __restrict__ dst, int K, int N)
{
    __shared__ float t[32][33];
    int bx = blockIdx.x, by = blockIdx.y;
    int col = threadIdx.x & 31, row8 = threadIdx.x >> 5;
    int gn = bx * 32 + col;
#pragma unroll
    for (int r = 0; r < 4; ++r) {
        int gk = by * 32 + row8 + r * 8;
        t[row8 + r * 8][col] = (gn < N) ? src[(size_t)gk * N + gn] : 0.f;
    }
    __syncthreads();
#pragma unroll
    for (int r = 0; r < 4; ++r) {
        int n = bx * 32 + row8 + r * 8;
        dst[(size_t)n * K + by * 32 + col] = f2bf(t[col][row8 + r * 8]);
    }
}

// ---------------- depthwise causal conv (k=4) + bias + silu, bf16 in/out ----
#define CTOK 8
__global__ __launch_bounds__(256) void conv_kernel(
    const short* __restrict__ zx, const float* __restrict__ cw,
    const float* __restrict__ cb, short* __restrict__ xBCc)
{
    int c4 = blockIdx.y * 256 + threadIdx.x;
    if (c4 >= CONV_DIM / 4) return;
    int c  = c4 * 4;
    int m0 = blockIdx.x * CTOK;
    int l0 = m0 & (SEQ - 1);

    const short* base = zx + (size_t)m0 * DPROJ + DIN + c;
    f32x4 win[CTOK + 3];
#pragma unroll
    for (int j = 0; j < CTOK + 3; ++j) {
        int off = j - 3;
        if (l0 + off >= 0) {
            short4 sv = *(const short4*)(base + (ptrdiff_t)off * DPROJ);
            win[j] = {bf2f(sv.x), bf2f(sv.y), bf2f(sv.z), bf2f(sv.w)};
        } else {
            win[j] = {0.f, 0.f, 0.f, 0.f};
        }
    }
    f32x4 w0 = *(const f32x4*)(cw + (c + 0) * DCONV);
    f32x4 w1 = *(const f32x4*)(cw + (c + 1) * DCONV);
    f32x4 w2 = *(const f32x4*)(cw + (c + 2) * DCONV);
    f32x4 w3 = *(const f32x4*)(cw + (c + 3) * DCONV);
    f32x4 bb = *(const f32x4*)(cb + c);

    short* outp = xBCc + (size_t)m0 * CONV_DIM + c;
#pragma unroll
    for (int t = 0; t < CTOK; ++t) {
        f32x4 a = {bb.x, bb.y, bb.z, bb.w};
#pragma unroll
        for (int j = 0; j < DCONV; ++j) {
            f32x4 v = win[t + j];
            a.x += v.x * w0[j];
            a.y += v.y * w1[j];
            a.z += v.z * w2[j];
            a.w += v.w * w3[j];
        }
        short4 o;
        o.x = f2bf(silu_f(a.x)); o.y = f2bf(silu_f(a.y));
        o.z = f2bf(silu_f(a.z)); o.w = f2bf(silu_f(a.w));
        *(short4*)(outp + (size_t)t * CONV_DIM) = o;
    }
}

// ---------------- dt = softplus(dt_raw + bias); ldA = A * dt ----------------
__global__ __launch_bounds__(256) void dt_kernel(
    const short* __restrict__ zx, const float* __restrict__ dt_bias,
    const float* __restrict__ A_log, float* __restrict__ dtb, float* __restrict__ ldab)
{
    int idx = blockIdx.x * 256 + threadIdx.x;
    if (idx >= TOKENS * NH) return;
    int hh = idx & (NH - 1);
    int m  = idx >> 5;
    float v  = bf2f(zx[(size_t)m * DPROJ + DIN + CONV_DIM + hh]) + dt_bias[hh];
    float dt = (v > 20.f) ? v : log1pf(__expf(v));
    dtb[idx]  = dt;
    ldab[idx] = -__expf(A_log[hh]) * dt;
}

// ---------------- P1: intra-chunk SSD (bf16 xBCc) ----------------
__global__ __launch_bounds__(256) void chunk_kernel(
    const short* __restrict__ xBCc, const float* __restrict__ dtb,
    const float* __restrict__ ldab, float* __restrict__ ybuf,
    float* __restrict__ Sbuf, float* __restrict__ cumdecay)
{
    int bid = blockIdx.x;
    int h = bid & 31, c = (bid >> 5) & 31, b = bid >> 10;
    int m0 = b * SEQ + c * Q;
    int tid = threadIdx.x;
    int wid = tid >> 6, lane = tid & 63, lm = lane & 15, lg = lane >> 4;

    __shared__ __attribute__((aligned(16))) short Cc[64 * LSTR];
    __shared__ __attribute__((aligned(16))) short Bb[64 * LSTR];
    __shared__ __attribute__((aligned(16))) short BwT[64 * LSTR];
    __shared__ __attribute__((aligned(16))) short Xt[64 * LSTR];
    __shared__ __attribute__((aligned(16))) short Mm[64 * LSTR];
    __shared__ float Lc[64], dtv[64];

    if (tid < 64) {
        int s = tid;
        size_t ix = (size_t)(m0 + s) * NH + h;
        float ld = ldab[ix];
        float dt = dtb[ix];
        float v = ld;
#pragma unroll
        for (int off = 1; off < 64; off <<= 1) {
            float o = __shfl_up(v, off);
            if (s >= off) v += o;
        }
        Lc[s] = v;
        dtv[s] = dt;
        cumdecay[(size_t)bid * 64 + s] = __expf(v);
    }
    {
        int row = tid >> 2, c0 = (tid & 3) * 16;
        const short* pB = xBCc + (size_t)(m0 + row) * CONV_DIM + DIN;
#pragma unroll
        for (int u = 0; u < 2; ++u) {
            short8 vb = *(const short8*)(pB + c0 + 8 * u);
            short8 vc = *(const short8*)(pB + DSTATE + c0 + 8 * u);
            *(short8*)&Bb[row * LSTR + c0 + 8 * u] = vb;
            *(short8*)&Cc[row * LSTR + c0 + 8 * u] = vc;
        }
    }
    __syncthreads();
    {
        int s = tid >> 2, c0 = (tid & 3) * 16;
        float w = dtv[s];
        float w2 = __expf(Lc[63] - Lc[s]);
        const short* pX = xBCc + (size_t)(m0 + s) * CONV_DIM + h * HEADDIM;
#pragma unroll
        for (int u = 0; u < 4; ++u) {
            short4 v = *(const short4*)(pX + c0 + 4 * u);
            Xt[(c0 + 4 * u + 0) * LSTR + s] = f2bf(bf2f(v.x) * w);
            Xt[(c0 + 4 * u + 1) * LSTR + s] = f2bf(bf2f(v.y) * w);
            Xt[(c0 + 4 * u + 2) * LSTR + s] = f2bf(bf2f(v.z) * w);
            Xt[(c0 + 4 * u + 3) * LSTR + s] = f2bf(bf2f(v.w) * w);
            short4 sb = *(short4*)&Bb[s * LSTR + c0 + 4 * u];
            BwT[(c0 + 4 * u + 0) * LSTR + s] = f2bf(bf2f(sb.x) * w2);
            BwT[(c0 + 4 * u + 1) * LSTR + s] = f2bf(bf2f(sb.y) * w2);
            BwT[(c0 + 4 * u + 2) * LSTR + s] = f2bf(bf2f(sb.z) * w2);
            BwT[(c0 + 4 * u + 3) * LSTR + s] = f2bf(bf2f(sb.w) * w2);
        }
    }
    __syncthreads();

    {
        bf16x8 af[2];
#pragma unroll
        for (int kk = 0; kk < 2; ++kk)
            af[kk] = ld_frag(&Cc[(wid * 16 + lm) * LSTR + kk * 32 + lg * 8]);
#pragma unroll
        for (int j = 0; j < 4; ++j) {
            f32x4 acc = {0.f, 0.f, 0.f, 0.f};
#pragma unroll
            for (int kk = 0; kk < 2; ++kk) {
                bf16x8 bf = ld_frag(&Bb[(j * 16 + lm) * LSTR + kk * 32 + lg * 8]);
                acc = __builtin_amdgcn_mfma_f32_16x16x32_bf16(af[kk], bf, acc, 0, 0, 0);
            }
            int s = j * 16 + lm;
            float Ls = Lc[s];
#pragma unroll
            for (int r = 0; r < 4; ++r) {
                int t = wid * 16 + lg * 4 + r;
                float val = (s <= t) ? acc[r] * __expf(Lc[t] - Ls) : 0.f;
                Mm[t * LSTR + s] = f2bf(val);
            }
        }
    }
    __syncthreads();

    {
        bf16x8 am[2], aw[2];
#pragma unroll
        for (int kk = 0; kk < 2; ++kk) {
            am[kk] = ld_frag(&Mm[(wid * 16 + lm) * LSTR + kk * 32 + lg * 8]);
            aw[kk] = ld_frag(&BwT[(wid * 16 + lm) * LSTR + kk * 32 + lg * 8]);
        }
#pragma unroll
        for (int j = 0; j < 4; ++j) {
            f32x4 a1 = {0.f, 0.f, 0.f, 0.f};
            f32x4 a2 = {0.f, 0.f, 0.f, 0.f};
#pragma unroll
            for (int kk = 0; kk < 2; ++kk) {
                bf16x8 bx = ld_frag(&Xt[(j * 16 + lm) * LSTR + kk * 32 + lg * 8]);
                a1 = __builtin_amdgcn_mfma_f32_16x16x32_bf16(am[kk], bx, a1, 0, 0, 0);
                a2 = __builtin_amdgcn_mfma_f32_16x16x32_bf16(aw[kk], bx, a2, 0, 0, 0);
            }
            int p = j * 16 + lm;
#pragma unroll
            for (int r = 0; r < 4; ++r) {
                int t = wid * 16 + lg * 4 + r;
                ybuf[(size_t)(m0 + t) * DIN + h * HEADDIM + p] = a1[r];
                Sbuf[(size_t)bid * 4096 + t * 64 + p] = a2[r];
            }
        }
    }
}

// ---------------- P2: inter-chunk state recurrence (256 blocks + prefetch) --
// 4 blocks per (b,h); each block owns a 1024-float stripe of the 64x64 state.
// Prefetch next chunk's S into registers before storing H (hides HBM latency
// that the old 64-block serial-load version exposed every iteration).
__global__ __launch_bounds__(256) void state_kernel(
    float* __restrict__ SH, const float* __restrict__ cumdecay)
{
    int bh = blockIdx.x >> 2, st = blockIdx.x & 3;
    int b = bh >> 5, h = bh & 31;
    size_t off = (size_t)st * 1024 + (size_t)threadIdx.x * 4;

    f32x4 H = {0.f, 0.f, 0.f, 0.f};
    int cid = b * NCHUNK * NH + h;
    f32x4 s_next = *(const f32x4*)(SH + (size_t)cid * 4096 + off);
    float cd_next = cumdecay[(size_t)cid * 64 + 63];

    for (int c = 0; c < NCHUNK; ++c) {
        f32x4 s = s_next;
        float cd = cd_next;
        size_t base = (size_t)cid * 4096 + off;
        if (c + 1 < NCHUNK) {
            int cid1 = cid + NH;
            s_next = *(const f32x4*)(SH + (size_t)cid1 * 4096 + off);
            cd_next = cumdecay[(size_t)cid1 * 64 + 63];
        }
        *(f32x4*)(SH + base) = H;
        H.x = cd * H.x + s.x;
        H.y = cd * H.y + s.y;
        H.z = cd * H.z + s.z;
        H.w = cd * H.w + s.w;
        cid += NH;
    }
}

// ---------------- P3: y += exp(Lc_t) * C_t @ H_in ----------------
__global__ __launch_bounds__(256) void inter_kernel(
    const short* __restrict__ xBCc, const float* __restrict__ Hin,
    const float* __restrict__ cumdecay, float* __restrict__ ybuf)
{
    int bid = blockIdx.x;
    int h = bid & 31, c = (bid >> 5) & 31, b = bid >> 10;
    int m0 = b * SEQ + c * Q;
    int tid = threadIdx.x;
    int wid = tid >> 6, lane = tid & 63, lm = lane & 15, lg = lane >> 4;

    __shared__ __attribute__((aligned(16))) short Cc[64 * LSTR];
    __shared__ __attribute__((aligned(16))) short HT[64 * LSTR];
    __shared__ float eLc[64];

    if (tid < 64) eLc[tid] = cumdecay[(size_t)bid * 64 + tid];
    {
        int row = tid >> 2, c0 = (tid & 3) * 16;
        const short* pC = xBCc + (size_t)(m0 + row) * CONV_DIM + DIN + DSTATE;
#pragma unroll
        for (int u = 0; u < 2; ++u) {
            short8 vc = *(const short8*)(pC + c0 + 8 * u);
            *(short8*)&Cc[row * LSTR + c0 + 8 * u] = vc;
        }
        const float* pH = Hin + (size_t)bid * 4096 + row * 64;
#pragma unroll
        for (int u = 0; u < 4; ++u) {
            f32x4 vh = *(const f32x4*)(pH + c0 + 4 * u);
            HT[(c0 + 4 * u + 0) * LSTR + row] = f2bf(vh.x);
            HT[(c0 + 4 * u + 1) * LSTR + row] = f2bf(vh.y);
            HT[(c0 + 4 * u + 2) * LSTR + row] = f2bf(vh.z);
            HT[(c0 + 4 * u + 3) * LSTR + row] = f2bf(vh.w);
        }
    }
    __syncthreads();

    bf16x8 af[2];
#pragma unroll
    for (int kk = 0; kk < 2; ++kk)
        af[kk] = ld_frag(&Cc[(wid * 16 + lm) * LSTR + kk * 32 + lg * 8]);
#pragma unroll
    for (int j = 0; j < 4; ++j) {
        f32x4 acc = {0.f, 0.f, 0.f, 0.f};
#pragma unroll
        for (int kk = 0; kk < 2; ++kk) {
            bf16x8 bh_ = ld_frag(&HT[(j * 16 + lm) * LSTR + kk * 32 + lg * 8]);
            acc = __builtin_amdgcn_mfma_f32_16x16x32_bf16(af[kk], bh_, acc, 0, 0, 0);
        }
        int p = j * 16 + lm;
#pragma unroll
        for (int r = 0; r < 4; ++r) {
            int t = wid * 16 + lg * 4 + r;
            size_t ya = (size_t)(m0 + t) * DIN + h * HEADDIM + p;
            ybuf[ya] += eLc[t] * acc[r];
        }
    }
}

// ---------------- ybf = bf16(rmsnorm((y + D*x) * silu(z), norm_w)) ----------------
__global__ __launch_bounds__(256) void norm1_kernel(
    const short* __restrict__ zx, const short* __restrict__ xBCc,
    const float* __restrict__ Dp, const float* __restrict__ y,
    short* __restrict__ ybf, const float* __restrict__ w)
{
    int m = blockIdx.x;
    int t = threadIdx.x;
    const short* zr = zx + (size_t)m * DPROJ;
    const short* xr = xBCc + (size_t)m * CONV_DIM;
    const float* yr = y + (size_t)m * DIN;
    float vals[8];
    float ss = 0.f;
#pragma unroll
    for (int j = 0; j < 8; ++j) {
        int i = j * 256 + t;
        float v = (yr[i] + Dp[i >> 6] * bf2f(xr[i])) * silu_f(bf2f(zr[i]));
        vals[j] = v;
        ss += v * v;
    }
#pragma unroll
    for (int o = 32; o >= 1; o >>= 1) ss += __shfl_xor(ss, o);
    __shared__ float wsum[4];
    if ((t & 63) == 0) wsum[t >> 6] = ss;
    __syncthreads();
    float tot = wsum[0] + wsum[1] + wsum[2] + wsum[3];
    float scale = rsqrtf(tot / (float)DIN + EPS);
#pragma unroll
    for (int j = 0; j < 8; ++j) {
        int i = j * 256 + t;
        ybf[(size_t)m * DIN + i] = f2bf(vals[j] * scale * w[i]);
    }
}

// ---------------- hnbf = bf16(rmsnorm(h, rms_w)) ----------------
__global__ __launch_bounds__(256) void norm2_kernel(
    const float* __restrict__ hb, short* __restrict__ hnbf, const float* __restrict__ w)
{
    int m = blockIdx.x;
    int t = threadIdx.x;
    const float* hr = hb + (size_t)m * DMODEL;
    float vals[4];
    float ss = 0.f;
#pragma unroll
    for (int j = 0; j < 4; ++j) {
        int i = j * 256 + t;
        float v = hr[i];
        vals[j] = v;
        ss += v * v;
    }
#pragma unroll
    for (int o = 32; o >= 1; o >>= 1) ss += __shfl_xor(ss, o);
    __shared__ float wsum[4];
    if ((t & 63) == 0) wsum[t >> 6] = ss;
    __syncthreads();
    float tot = wsum[0] + wsum[1] + wsum[2] + wsum[3];
    float scale = rsqrtf(tot / (float)DMODEL + EPS);
#pragma unroll
    for (int j = 0; j < 4; ++j) {
        int i = j * 256 + t;
        hnbf[(size_t)m * DMODEL + i] = f2bf(vals[j] * scale * w[i]);
    }
}

extern "C" void kernel_launch(void* const* d_in, const int* in_sizes, int n_in,
                              void* d_out, int out_size, void* d_ws, size_t ws_size,
                              hipStream_t stream) {
    const float* x       = (const float*)d_in[0];
    const float* W_in    = (const float*)d_in[1];
    const float* conv_w  = (const float*)d_in[2];
    const float* conv_b  = (const float*)d_in[3];
    const float* dt_bias = (const float*)d_in[4];
    const float* A_log   = (const float*)d_in[5];
    const float* D_param = (const float*)d_in[6];
    const float* norm_w  = (const float*)d_in[7];
    const float* W_out   = (const float*)d_in[8];
    const float* rms_w   = (const float*)d_in[9];
    const float* mlp_w1  = (const float*)d_in[10];
    const float* mlp_b1  = (const float*)d_in[11];
    const float* mlp_w2  = (const float*)d_in[12];
    const float* mlp_b2  = (const float*)d_in[13];
    float* out = (float*)d_out;

    float* ws       = (float*)d_ws;
    float* zxf      = ws;                                  // holds bf16 zx
    float* xBCf     = zxf + (size_t)TOKENS * DPROJ;        // holds bf16 xBCc
    float* dtb      = xBCf + (size_t)TOKENS * CONV_DIM;
    float* ldab     = dtb + (size_t)TOKENS * NH;
    float* cumdecay = ldab + (size_t)TOKENS * NH;
    float* ybuf     = cumdecay + (size_t)TOKENS * NH;
    float* SH       = ybuf + (size_t)TOKENS * DIN;
    float* bfarea   = SH + (size_t)NCH * 4096;

    short* zxb   = (short*)zxf;
    short* xBCb  = (short*)xBCf;
    short* xbf   = (short*)ybuf;
    short* midbf = (short*)ybuf;
    float* hbuf  = SH;
    short* hnbf  = (short*)(SH + (size_t)TOKENS * DMODEL);

    short* ybf   = (short*)bfarea;
    short* WinT  = ybf + (size_t)TOKENS * DIN;
    short* WoutT = WinT + (size_t)NPAD_IN * DMODEL;
    short* w1T   = WoutT + (size_t)DMODEL * DIN;
    short* w2T   = w1T + (size_t)MLP_INNER * DMODEL;

    dim3 blk(256);
    dim3 blk2(512);

    // 0. conversions / weight transposes
    cvt_kernel<<<dim3(TOKENS * DMODEL / 4 / 256), blk, 0, stream>>>(x, xbf, TOKENS * DMODEL / 4);
    transpose_kernel<<<dim3(NPAD_IN / 32, DMODEL / 32), blk, 0, stream>>>(W_in, WinT, DMODEL, DPROJ);
    transpose_kernel<<<dim3(DMODEL / 32, DIN / 32), blk, 0, stream>>>(W_out, WoutT, DIN, DMODEL);
    transpose_kernel<<<dim3(MLP_INNER / 32, DMODEL / 32), blk, 0, stream>>>(mlp_w1, w1T, DMODEL, MLP_INNER);
    transpose_kernel<<<dim3(DMODEL / 32, MLP_INNER / 32), blk, 0, stream>>>(mlp_w2, w2T, MLP_INNER, DMODEL);

    // 1. zx = bf16(x @ W_in)  (1088 blocks -> 128^2 KT=32 path, 4 blk/CU)
    gemm_bf16_kernel<4, 32><<<dim3(NPAD_IN / 128, TOKENS / 128), blk, 0, stream>>>(
        xbf, WinT, zxb, nullptr, nullptr, TOKENS, DPROJ, DMODEL);
    // 2. conv + bias + silu (bf16 in/out, token-blocked)
    conv_kernel<<<dim3(TOKENS / CTOK, (CONV_DIM / 4 + 255) / 256), blk, 0, stream>>>(
        zxb, conv_w, conv_b, xBCb);
    // 3. dt / ldA
    dt_kernel<<<dim3(TOKENS * NH / 256), blk, 0, stream>>>(zxb, dt_bias, A_log, dtb, ldab);
    // 4. SSD
    chunk_kernel<<<dim3(NCH), blk, 0, stream>>>(xBCb, dtb, ldab, ybuf, SH, cumdecay);
    state_kernel<<<dim3(BATCH * NH * 4), blk, 0, stream>>>(SH, cumdecay);
    inter_kernel<<<dim3(NCH), blk, 0, stream>>>(xBCb, SH, cumdecay, ybuf);
    // 5. ybf = bf16(rmsnorm((y + D*x) * silu(z)))
    norm1_kernel<<<dim3(TOKENS), blk, 0, stream>>>(zxb, xBCb, D_param, ybuf, ybf, norm_w);
    // 6. h = x + ybf @ W_out  (64x128 tiles: 8 x 64 = 512 blocks, 2 blk/CU)
    gemm64_kernel<3><<<dim3(DMODEL / 128, TOKENS / 64), blk, 0, stream>>>(
        ybf, WoutT, hbuf, nullptr, x, TOKENS, DMODEL, DIN);
    // 7. hnbf = bf16(rmsnorm(h))
    norm2_kernel<<<dim3(TOKENS), blk, 0, stream>>>(hbuf, hnbf, rms_w);
    // 8. midbf = bf16(silu(hnbf @ mlp_w1 + b1))  (256^2 phased: 256 blocks, 1 round)
    gemm256_kernel<1><<<dim3(MLP_INNER / 256, TOKENS / 256), blk2, 0, stream>>>(
        hnbf, w1T, midbf, mlp_b1, TOKENS, MLP_INNER, DMODEL);
    // 9. out = h + midbf @ mlp_w2 + b2  (64x128 tiles: 512 blocks, 2 blk/CU)
    gemm64_kernel<2><<<dim3(DMODEL / 128, TOKENS / 64), blk, 0, stream>>>(
        midbf, w2T, out, mlp_b2, hbuf, TOKENS, DMODEL, MLP_INNER);
}